// Round 1
// baseline (182.252 us; speedup 1.0000x reference)
//
#include <hip/hip_runtime.h>
#include <hip/hip_bf16.h>
#include <stdint.h>

typedef unsigned short u16;
typedef __attribute__((ext_vector_type(8))) short bf16x8;
typedef __attribute__((ext_vector_type(4))) float f32x4;
typedef __attribute__((ext_vector_type(16))) float f32x16;

#define AS1 __attribute__((address_space(1)))
#define AS3 __attribute__((address_space(3)))

__device__ __forceinline__ u16 f2bf(float f) {
  union { float f; uint32_t u; } v; v.f = f;
  uint32_t u = v.u;
  return (u16)((u + 0x7FFFu + ((u >> 16) & 1u)) >> 16);
}

// packed f32x2 -> bf16x2 (RNE), single instruction
__device__ __forceinline__ uint32_t cvtpk(float lo, float hi) {
  uint32_t d;
  asm("v_cvt_pk_bf16_f32 %0, %1, %2" : "=v"(d) : "v"(lo), "v"(hi));
  return d;
}

// ---------------- fp32 -> bf16 convert ----------------
__global__ __launch_bounds__(256) void cvt_kernel(const float* __restrict__ src,
                                                  u16* __restrict__ dst, int n4) {
  int i = blockIdx.x * 256 + threadIdx.x;
  if (i >= n4) return;
  float4 v = reinterpret_cast<const float4*>(src)[i];
  uint2 o;
  o.x = cvtpk(v.x, v.y);
  o.y = cvtpk(v.z, v.w);
  reinterpret_cast<uint2*>(dst)[i] = o;
}

__global__ __launch_bounds__(256) void cvt4_kernel(const float* __restrict__ s0,
    const float* __restrict__ s1, const float* __restrict__ s2, const float* __restrict__ s3,
    u16* __restrict__ d0, u16* __restrict__ d1, u16* __restrict__ d2, u16* __restrict__ d3, int n4) {
  int i = blockIdx.x * 256 + threadIdx.x;
  if (i >= n4) return;
  const float* s = (blockIdx.y == 0) ? s0 : (blockIdx.y == 1) ? s1 : (blockIdx.y == 2) ? s2 : s3;
  u16* d = (blockIdx.y == 0) ? d0 : (blockIdx.y == 1) ? d1 : (blockIdx.y == 2) ? d2 : d3;
  float4 v = reinterpret_cast<const float4*>(s)[i];
  uint2 o;
  o.x = cvtpk(v.x, v.y);
  o.y = cvtpk(v.z, v.w);
  reinterpret_cast<uint2*>(d)[i] = o;
}

// Q pre-scaled by 1/sqrt(d_k) * log2(e) so attention uses raw exp2.
#define QSCALE 0.18033688011112042f

// ---------------- old 128x128 GEMM body (kept for gemm_out) ----------------
#define BM 128
#define BN 128
#define BKK 32

template <int MODE, typename OutT>
__device__ __forceinline__ void gemm_bt_body(const u16* __restrict__ A, const u16* __restrict__ Bm,
                                             OutT* __restrict__ C, int M, int N, int K,
                                             int by, int bx, float oscale) {
  __shared__ u16 As[BM * BKK];
  __shared__ u16 Bs[BN * BKK];
  const int tid = threadIdx.x;
  const int lane = tid & 63;
  const int wave = tid >> 6;
  const int wr = wave >> 1, wc = wave & 1;
  const int l15 = lane & 15, lhi = lane >> 4;
  const int rowA0 = by * BM, colB0 = bx * BN;

  const f32x4 fzero = {0.f, 0.f, 0.f, 0.f};
  f32x4 acc[4][4];
#pragma unroll
  for (int m = 0; m < 4; ++m)
#pragma unroll
    for (int n = 0; n < 4; ++n) acc[m][n] = fzero;

  for (int k0 = 0; k0 < K; k0 += BKK) {
#pragma unroll
    for (int c = 0; c < 2; ++c) {
      const int chunk = wave * 2 + c;
      const int elem = chunk * 512 + lane * 8;
      const int r = elem >> 5;
      const int cc = elem & 31;
      const u16* gA = A + (size_t)(rowA0 + r) * K + k0 + cc;
      const u16* gB = Bm + (size_t)(colB0 + r) * K + k0 + cc;
      __builtin_amdgcn_global_load_lds((const AS1 uint32_t*)gA,
                                       (AS3 uint32_t*)(As + chunk * 512), 16, 0, 0);
      __builtin_amdgcn_global_load_lds((const AS1 uint32_t*)gB,
                                       (AS3 uint32_t*)(Bs + chunk * 512), 16, 0, 0);
    }
    __syncthreads();

    bf16x8 af[4], bfr[4];
#pragma unroll
    for (int m = 0; m < 4; ++m)
      af[m] = *reinterpret_cast<const bf16x8*>(&As[(wr * 64 + m * 16 + l15) * BKK + lhi * 8]);
#pragma unroll
    for (int n = 0; n < 4; ++n)
      bfr[n] = *reinterpret_cast<const bf16x8*>(&Bs[(wc * 64 + n * 16 + l15) * BKK + lhi * 8]);
#pragma unroll
    for (int m = 0; m < 4; ++m)
#pragma unroll
      for (int n = 0; n < 4; ++n)
        acc[m][n] = __builtin_amdgcn_mfma_f32_16x16x32_bf16(af[m], bfr[n], acc[m][n], 0, 0, 0);
    __syncthreads();
  }

#pragma unroll
  for (int m = 0; m < 4; ++m)
#pragma unroll
    for (int n = 0; n < 4; ++n) {
      const int row0 = rowA0 + wr * 64 + m * 16 + lhi * 4;
      const int col = colB0 + wc * 64 + n * 16 + l15;
      if constexpr (MODE == 2) {
        uint2 pk;
        pk.x = cvtpk(acc[m][n][0], acc[m][n][1]);
        pk.y = cvtpk(acc[m][n][2], acc[m][n][3]);
        *reinterpret_cast<uint2*>((u16*)C + (size_t)col * M + row0) = pk;
      } else if constexpr (MODE == 1) {
#pragma unroll
        for (int r = 0; r < 4; ++r)
          ((float*)C)[(size_t)(row0 + r) * N + col] = acc[m][n][r];
      } else {
#pragma unroll
        for (int r = 0; r < 4; ++r)
          ((u16*)C)[(size_t)(row0 + r) * N + col] = f2bf(acc[m][n][r] * oscale);
      }
    }
}

__global__ __launch_bounds__(256) void gemm_out_kernel(const u16* __restrict__ A,
    const u16* __restrict__ Bm, float* __restrict__ C, int M, int N, int K) {
  const int id = blockIdx.x;           // 0..511
  const int xcd = id & 7;
  const int slot = id >> 3;            // 0..63
  const int byi = slot & 7;
  const int bx = slot >> 3;            // 0..7
  const int by = xcd + 8 * byi;
  gemm_bt_body<1, float>(A, Bm, C, M, N, K, by, bx, 1.f);
}

// ---------------- NEW: 256x256 / BK=64 / 8-wave 8-phase GEMM for QKV ----------------
// C = A * B^T. LDS 128 KB: [buf 0/1][A|B][256 rows][64 k] bf16, XOR-swizzled
// byte ^= ((row&7)<<4) (16B-slot involution). global_load_lds writes linearly, so the
// GLOBAL source address is pre-swizzled with the same XOR; ds_read_b128 applies it too.
// Pipeline: tile staged as 4 quarters (2 loads each). Boundary of tile t issues
// t+2 q0..q2 (buffer freed, all reads drained) then s_waitcnt vmcnt(6) -> drains
// t+1's last quarter while 6 loads stay in flight across the barrier. Phase 1 of
// each tile issues the next tile's q3. Never vmcnt(0) in steady state.
#define GBK 64

template <int MODE, typename OutT>
__device__ __forceinline__ void gemm256_body(u16* __restrict__ lds,
    const u16* __restrict__ A, const u16* __restrict__ Bm, OutT* __restrict__ C,
    int M, int N, int K, int by, int bx, float oscale) {
  const int tid = threadIdx.x;
  const int lane = tid & 63;
  const int wave = tid >> 6;                 // 0..7
  const int wm = wave >> 2, wn = wave & 3;   // 2 x 4 waves; per-wave tile 128(M) x 64(N)
  const int l15 = lane & 15, lhi = lane >> 4;
  const int axor = (lane & 7) << 4;          // row&7 == lane&7 for all frag reads

  // staging: thread -> (row = q*64 + tid>>3, 16B slot = (tid&7) ^ (row&7))
  const int srow = tid >> 3;                               // 0..63 within quarter
  const int scol = (((tid & 7) ^ (srow & 7)) << 4);        // pre-swizzled source col byte
  const size_t Kb = (size_t)K * 2;
  const uint8_t* Ag = (const uint8_t*)A + (size_t)(by * 256 + srow) * Kb + scol;
  const uint8_t* Bg = (const uint8_t*)Bm + (size_t)(bx * 256 + srow) * Kb + scol;
  uint8_t* Lb = (uint8_t*)lds;  // [buf*65536 | +32768 for B][q*8192 + tid*16]

#define STG(bufi, kt, q)                                                                   \
  do {                                                                                     \
    __builtin_amdgcn_global_load_lds(                                                      \
        (const AS1 uint32_t*)(Ag + (size_t)(q) * 64 * Kb + (size_t)(kt) * 128),            \
        (AS3 uint32_t*)(Lb + (bufi) * 65536 + (q) * 8192 + tid * 16), 16, 0, 0);           \
    __builtin_amdgcn_global_load_lds(                                                      \
        (const AS1 uint32_t*)(Bg + (size_t)(q) * 64 * Kb + (size_t)(kt) * 128),            \
        (AS3 uint32_t*)(Lb + (bufi) * 65536 + 32768 + (q) * 8192 + tid * 16), 16, 0, 0);   \
  } while (0)

#define RD_A(mh)                                                                           \
  do {                                                                                     \
    _Pragma("unroll") for (int mm = 0; mm < 4; ++mm)                                       \
      _Pragma("unroll") for (int ks = 0; ks < 2; ++ks)                                     \
        aF[mm][ks] = *reinterpret_cast<const bf16x8*>(                                     \
            Ab + (wm * 128 + (mh) * 64 + mm * 16 + l15) * 128 +                            \
                 ((ks * 64 + lhi * 16) ^ axor));                                           \
  } while (0)

#define RD_B(nh)                                                                           \
  do {                                                                                     \
    _Pragma("unroll") for (int nn = 0; nn < 2; ++nn)                                       \
      _Pragma("unroll") for (int ks = 0; ks < 2; ++ks)                                     \
        bF[nn][ks] = *reinterpret_cast<const bf16x8*>(                                     \
            Bb + (wn * 64 + (nh) * 32 + nn * 16 + l15) * 128 +                             \
                 ((ks * 64 + lhi * 16) ^ axor));                                           \
  } while (0)

#define MFMA_Q(mh, nh)                                                                     \
  do {                                                                                     \
    asm volatile("s_waitcnt lgkmcnt(0)" ::: "memory");                                     \
    __builtin_amdgcn_sched_barrier(0);                                                     \
    __builtin_amdgcn_s_setprio(1);                                                         \
    _Pragma("unroll") for (int mm = 0; mm < 4; ++mm)                                       \
      _Pragma("unroll") for (int nn = 0; nn < 2; ++nn)                                     \
        _Pragma("unroll") for (int ks = 0; ks < 2; ++ks)                                   \
          acc[(mh) * 4 + mm][(nh) * 2 + nn] = __builtin_amdgcn_mfma_f32_16x16x32_bf16(     \
              aF[mm][ks], bF[nn][ks], acc[(mh) * 4 + mm][(nh) * 2 + nn], 0, 0, 0);         \
    __builtin_amdgcn_s_setprio(0);                                                         \
  } while (0)

  const f32x4 fzero = {0.f, 0.f, 0.f, 0.f};
  f32x4 acc[8][4];
#pragma unroll
  for (int m = 0; m < 8; ++m)
#pragma unroll
    for (int n = 0; n < 4; ++n) acc[m][n] = fzero;

  const int NT = K / GBK;

  // prologue: tile0 fully + tile1 q0..q2; drain tile0 only (6 left in flight)
  STG(0, 0, 0); STG(0, 0, 1); STG(0, 0, 2); STG(0, 0, 3);
  if (NT > 1) {
    STG(1, 1, 0); STG(1, 1, 1); STG(1, 1, 2);
    asm volatile("s_waitcnt vmcnt(6)" ::: "memory");
  } else {
    asm volatile("s_waitcnt vmcnt(0)" ::: "memory");
  }
  __builtin_amdgcn_s_barrier();

  bf16x8 aF[4][2], bF[2][2];
  for (int t = 0; t < NT; ++t) {
    const int pb = t & 1;
    const uint8_t* Ab = Lb + pb * 65536;
    const uint8_t* Bb = Ab + 32768;

    // ---- phase 1: quadrant (mh0, nh0); issue next tile's q3 ----
    RD_A(0); RD_B(0);
    if (t + 1 < NT) STG(pb ^ 1, t + 1, 3);
    __builtin_amdgcn_s_barrier();
    MFMA_Q(0, 0);
    __builtin_amdgcn_s_barrier();
    // ---- phase 2: (mh0, nh1) ----
    RD_B(1);
    __builtin_amdgcn_s_barrier();
    MFMA_Q(0, 1);
    __builtin_amdgcn_s_barrier();
    // ---- phase 3: (mh1, nh1) ----
    RD_A(1);
    __builtin_amdgcn_s_barrier();
    MFMA_Q(1, 1);
    __builtin_amdgcn_s_barrier();
    // ---- phase 4: (mh1, nh0) ----
    RD_B(0);
    __builtin_amdgcn_s_barrier();
    MFMA_Q(1, 0);
    __builtin_amdgcn_s_barrier();   // all reads of buf pb drained & all waves past
    // ---- boundary: refill freed buffer, counted drain, swap ----
    if (t + 1 < NT) {
      if (t + 2 < NT) {
        STG(pb, t + 2, 0); STG(pb, t + 2, 1); STG(pb, t + 2, 2);
        asm volatile("s_waitcnt vmcnt(6)" ::: "memory");  // drains t+1's q3; 6 stay in flight
      } else {
        asm volatile("s_waitcnt vmcnt(0)" ::: "memory");  // last boundary: full drain
      }
      __builtin_amdgcn_s_barrier();
    }
  }

  // ---- epilogue ----
#pragma unroll
  for (int mf = 0; mf < 8; ++mf)
#pragma unroll
    for (int nf = 0; nf < 4; ++nf) {
      const int row0 = by * 256 + wm * 128 + mf * 16 + lhi * 4;
      const int col = bx * 256 + wn * 64 + nf * 16 + l15;
      if constexpr (MODE == 2) {
        uint2 pk;
        pk.x = cvtpk(acc[mf][nf][0], acc[mf][nf][1]);
        pk.y = cvtpk(acc[mf][nf][2], acc[mf][nf][3]);
        *reinterpret_cast<uint2*>((u16*)C + (size_t)col * M + row0) = pk;
      } else if constexpr (MODE == 1) {
#pragma unroll
        for (int r = 0; r < 4; ++r)
          ((float*)C)[(size_t)(row0 + r) * N + col] = acc[mf][nf][r];
      } else {
#pragma unroll
        for (int r = 0; r < 4; ++r)
          ((u16*)C)[(size_t)(row0 + r) * N + col] = f2bf(acc[mf][nf][r] * oscale);
      }
    }
#undef STG
#undef RD_A
#undef RD_B
#undef MFMA_Q
}

// XCD-aware: id%8 = XCD; per XCD, 12 consecutive slots (4bx x 3bz) share one A-row
// panel (512 KB) so it stays L2-resident. 384 = 8 xcd x 4 byi x 4 bx x 3 bz.
__global__ __launch_bounds__(512, 2) void gemm_qkv_kernel(const u16* __restrict__ A,
    const u16* __restrict__ W0, const u16* __restrict__ W1, const u16* __restrict__ W2,
    u16* __restrict__ OQ, u16* __restrict__ OK, u16* __restrict__ OVT, int M, int N, int K) {
  __shared__ u16 lds[2][2][256 * GBK];  // 128 KB
  const int id = blockIdx.x;            // 0..383
  const int xcd = id & 7;
  const int slot = id >> 3;             // 0..47
  const int byi = slot / 12;            // 0..3
  const int c = slot - byi * 12;        // 0..11
  const int bx = c & 3;
  const int bz = c >> 2;                // 0..2
  const int by = xcd + 8 * byi;         // 0..31
  if (bz == 0)      gemm256_body<0, u16>(&lds[0][0][0], A, W0, OQ,  M, N, K, by, bx, QSCALE);
  else if (bz == 1) gemm256_body<0, u16>(&lds[0][0][0], A, W1, OK,  M, N, K, by, bx, 1.f);
  else              gemm256_body<2, u16>(&lds[0][0][0], A, W2, OVT, M, N, K, by, bx, 1.f);
}

// ---------------- causal flash attention v6: 32x32 MFMA, in-register P ----------------
#define KVB 64

__global__ __launch_bounds__(512, 4) void attn_kernel(const u16* __restrict__ Q,
    const u16* __restrict__ Kg, const u16* __restrict__ VTg, u16* __restrict__ O,
    int S, int H, int Dm, int T) {
  const int bh = blockIdx.x;
  const int b = bh / H, h = bh % H;
  const int by = blockIdx.y;
  const int y = (by < 4) ? (7 - by) : (by - 4);
  const int qH = 1024 + y * 128;
  const int qL = 896 - y * 128;
  const int tid = threadIdx.x;
  const int lane = tid & 63, wave = tid >> 6;
  const int l31 = lane & 31, hi = lane >> 5;

  __shared__ u16 KVs[2][2][64 * 64];  // [buf][K=0/V=1], col-block swizzle ^((row&7)<<3)  (32KB)

  const u16* Qh = Q + ((size_t)b * S) * Dm + h * 64;
  const u16* Kh = Kg + ((size_t)b * S) * Dm + h * 64;
  const u16* Vh = VTg + (size_t)(h * 64) * T + (size_t)b * S;
  const int qv = (wave < 4) ? (qH + wave * 32) : (qL + (wave - 4) * 32);
  const int qr = qv + l31;

  // Q frags (B-operand 32x32x16): col = q = l31, k = dc*16 + hi*8 + j
  bf16x8 qf[4];
#pragma unroll
  for (int dc = 0; dc < 4; ++dc)
    qf[dc] = *reinterpret_cast<const bf16x8*>(Qh + (size_t)qr * Dm + dc * 16 + hi * 8);

  f32x16 acc[2];  // O^T: d = db*32 + (reg&3)+8*(reg>>2)+4*hi, q = l31
#pragma unroll
  for (int db = 0; db < 2; ++db)
#pragma unroll
    for (int r = 0; r < 16; ++r) acc[db][r] = 0.f;
  float mrow = -1e30f, lrow = 0.f;

#define STAGE(bufi, kvoff)                                                                     \
  do {                                                                                         \
    const int srow = tid >> 3;                                                                 \
    const int scol = (((tid & 7) ^ (srow & 7)) << 3);                                          \
    __builtin_amdgcn_global_load_lds(                                                          \
        (const AS1 uint32_t*)(Kh + (size_t)((kvoff) + srow) * Dm + scol),                      \
        (AS3 uint32_t*)(&KVs[bufi][0][tid * 8]), 16, 0, 0);                                    \
    __builtin_amdgcn_global_load_lds(                                                          \
        (const AS1 uint32_t*)(Vh + (size_t)srow * T + (kvoff) + scol),                         \
        (AS3 uint32_t*)(&KVs[bufi][1][tid * 8]), 16, 0, 0);                                    \
  } while (0)

  const int nt = qH / 64 + 2;
  STAGE(0, 0);
  int buf = 0;

  for (int t = 0; t < nt; ++t) {
    __syncthreads();
    const int kv = t * KVB;
    if (t + 1 < nt) STAGE(buf ^ 1, (t + 1) * KVB);

    if (kv <= qv + 31) {
      const u16* KB = KVs[buf][0];
      const u16* VB = KVs[buf][1];

      // ---- QK^T: sc[b] covers kv rows b*32..b*32+31, q = l31 ----
      f32x16 sc[2];
#pragma unroll
      for (int bb = 0; bb < 2; ++bb) {
#pragma unroll
        for (int r = 0; r < 16; ++r) sc[bb][r] = 0.f;
#pragma unroll
        for (int dc = 0; dc < 4; ++dc) {
          const bf16x8 kf = *reinterpret_cast<const bf16x8*>(
              KB + (bb * 32 + l31) * 64 + (((dc * 2 + hi) ^ (l31 & 7)) << 3));
          sc[bb] = __builtin_amdgcn_mfma_f32_32x32x16_bf16(kf, qf[dc], sc[bb], 0, 0, 0);
        }
      }

      // ---- causal mask + row max (31 in-reg fmax + 1 shfl) ----
      const bool msk = (kv + KVB - 1 > qv);
      float bmax = -3e38f;
#pragma unroll
      for (int bb = 0; bb < 2; ++bb)
#pragma unroll
        for (int r = 0; r < 16; ++r) {
          float v = sc[bb][r];
          if (msk) {
            const int kvg = kv + bb * 32 + (r & 3) + 8 * (r >> 2) + 4 * hi;
            v = (kvg > qr) ? -1e30f : v;
            sc[bb][r] = v;
          }
          bmax = fmaxf(bmax, v);
        }
      bmax = fmaxf(bmax, __shfl_xor(bmax, 32, 64));

      // ---- defer-max rescale ----
      if (!__all(bmax <= mrow + 6.f)) {
        const float mn = fmaxf(mrow, bmax);
        const float fac = __builtin_amdgcn_exp2f(mrow - mn);
        mrow = mn;
        lrow *= fac;
#pragma unroll
        for (int db = 0; db < 2; ++db)
#pragma unroll
          for (int r = 0; r < 16; ++r) acc[db][r] *= fac;
      }

      // ---- exp2 + per-lane partial sum ----
      float rs = 0.f;
#pragma unroll
      for (int bb = 0; bb < 2; ++bb)
#pragma unroll
        for (int r = 0; r < 16; ++r) {
          const float p = __builtin_amdgcn_exp2f(sc[bb][r] - mrow);
          sc[bb][r] = p;
          rs += p;
        }
      lrow += rs;

      // ---- PV: per 16-kv chunk, build P B-frag in regs via cvt_pk + permlane32_swap ----
#pragma unroll
      for (int cc = 0; cc < 4; ++cc) {
        const int bb = cc >> 1, c2 = cc & 1;
        uint32_t a0 = cvtpk(sc[bb][8 * c2 + 0], sc[bb][8 * c2 + 1]);
        uint32_t a1 = cvtpk(sc[bb][8 * c2 + 2], sc[bb][8 * c2 + 3]);
        uint32_t b0 = cvtpk(sc[bb][8 * c2 + 4], sc[bb][8 * c2 + 5]);
        uint32_t b1 = cvtpk(sc[bb][8 * c2 + 6], sc[bb][8 * c2 + 7]);
        asm("v_permlane32_swap_b32 %0, %1" : "+v"(a0), "+v"(b0));
        asm("v_permlane32_swap_b32 %0, %1" : "+v"(a1), "+v"(b1));
        union { uint32_t u[4]; bf16x8 v8; } pf;
        pf.u[0] = a0; pf.u[1] = a1; pf.u[2] = b0; pf.u[3] = b1;
#pragma unroll
        for (int db = 0; db < 2; ++db) {
          const bf16x8 vfg = *reinterpret_cast<const bf16x8*>(
              VB + (db * 32 + l31) * 64 + (((cc * 2 + hi) ^ (l31 & 7)) << 3));
          acc[db] = __builtin_amdgcn_mfma_f32_32x32x16_bf16(vfg, pf.v8, acc[db], 0, 0, 0);
        }
      }
    }
    buf ^= 1;
  }

  // ---- epilogue: finish l, O^T regs -> LDS (row-swizzled) -> coalesced 16B stores ----
  lrow += __shfl_xor(lrow, 32, 64);
  const float inv = 1.f / lrow;
  __syncthreads();
  u16* Ost = &KVs[0][0][0];  // 32 KB = [256 rows][64 d], 8-elem col-blocks swizzled by row&7
  {
    const int row = wave * 32 + l31;
#pragma unroll
    for (int db = 0; db < 2; ++db)
#pragma unroll
      for (int g = 0; g < 4; ++g) {
        uint2 pk;
        pk.x = cvtpk(acc[db][4 * g + 0] * inv, acc[db][4 * g + 1] * inv);
        pk.y = cvtpk(acc[db][4 * g + 2] * inv, acc[db][4 * g + 3] * inv);
        const int blk = 4 * db + g;  // d = db*32 + 8g + 4hi + 0..3
        const int addr = row * 64 + (((blk ^ (row & 7)) << 3)) + 4 * hi;
        *reinterpret_cast<uint2*>(Ost + addr) = pk;
      }
  }
  __syncthreads();
#pragma unroll
  for (int p = 0; p < 4; ++p) {
    const int idx = p * 512 + tid;
    const int row = idx >> 3, seg = idx & 7;
    const float4 v = *reinterpret_cast<const float4*>(Ost + row * 64 + ((seg ^ (row & 7)) << 3));
    const int q = (row < 128) ? (qH + row) : (qL + row - 128);
    *reinterpret_cast<float4*>(O + ((size_t)b * S + q) * Dm + h * 64 + seg * 8) = v;
  }
#undef STAGE
}

// ---------------- launch ----------------
extern "C" void kernel_launch(void* const* d_in, const int* in_sizes, int n_in,
                              void* d_out, int out_size, void* d_ws, size_t ws_size,
                              hipStream_t stream) {
  const float* x  = (const float*)d_in[0];
  const float* Wq = (const float*)d_in[1];
  const float* Wk = (const float*)d_in[2];
  const float* Wv = (const float*)d_in[3];
  const float* Wo = (const float*)d_in[4];
  float* out = (float*)d_out;

  const int B = 4, S = 2048, D = 1024, H = 16;
  const int T = B * S;  // 8192

  uint8_t* p = (uint8_t*)d_ws;
  u16* xb  = (u16*)p; p += (size_t)T * D * 2;
  u16* wqb = (u16*)p; p += (size_t)D * D * 2;
  u16* wkb = (u16*)p; p += (size_t)D * D * 2;
  u16* wvb = (u16*)p; p += (size_t)D * D * 2;
  u16* wob = (u16*)p; p += (size_t)D * D * 2;
  u16* Qb  = (u16*)p; p += (size_t)T * D * 2;
  u16* Kb  = (u16*)p; p += (size_t)T * D * 2;
  u16* VTb = (u16*)p; p += (size_t)D * T * 2;  // V^T [D][T]
  u16* Ab  = xb;  // xb dead after QKV gemm -> reuse for attn output

  cvt_kernel<<<dim3(T * D / 4 / 256), dim3(256), 0, stream>>>(x, xb, T * D / 4);
  cvt4_kernel<<<dim3(D * D / 4 / 256, 4), dim3(256), 0, stream>>>(
      Wq, Wk, Wv, Wo, wqb, wkb, wvb, wob, D * D / 4);

  // 256^2 8-phase QKV: 32 Mtiles x 4 Ntiles x 3 GEMMs = 384 blocks of 512
  gemm_qkv_kernel<<<dim3(384), dim3(512), 0, stream>>>(xb, wqb, wkb, wvb, Qb, Kb, VTb, T, D, D);

  // grid: x = bh (XCD locality), y = 8 paired q-range blocks
  attn_kernel<<<dim3(B * H, 8), dim3(512), 0, stream>>>(Qb, Kb, VTb, Ab, S, H, D, T);

  gemm_out_kernel<<<dim3(512), dim3(256), 0, stream>>>(Ab, wob, out, T, D, D);
}

// Round 2
// 177.648 us; speedup vs baseline: 1.0259x; 1.0259x over previous
//
#include <hip/hip_runtime.h>
#include <hip/hip_bf16.h>
#include <stdint.h>

typedef unsigned short u16;
typedef __attribute__((ext_vector_type(8))) short bf16x8;
typedef __attribute__((ext_vector_type(4))) float f32x4;
typedef __attribute__((ext_vector_type(16))) float f32x16;

#define AS1 __attribute__((address_space(1)))
#define AS3 __attribute__((address_space(3)))

__device__ __forceinline__ u16 f2bf(float f) {
  union { float f; uint32_t u; } v; v.f = f;
  uint32_t u = v.u;
  return (u16)((u + 0x7FFFu + ((u >> 16) & 1u)) >> 16);
}

// packed f32x2 -> bf16x2 (RNE), single instruction
__device__ __forceinline__ uint32_t cvtpk(float lo, float hi) {
  uint32_t d;
  asm("v_cvt_pk_bf16_f32 %0, %1, %2" : "=v"(d) : "v"(lo), "v"(hi));
  return d;
}

// ---------------- fp32 -> bf16 convert ----------------
__global__ __launch_bounds__(256) void cvt_kernel(const float* __restrict__ src,
                                                  u16* __restrict__ dst, int n4) {
  int i = blockIdx.x * 256 + threadIdx.x;
  if (i >= n4) return;
  float4 v = reinterpret_cast<const float4*>(src)[i];
  uint2 o;
  o.x = cvtpk(v.x, v.y);
  o.y = cvtpk(v.z, v.w);
  reinterpret_cast<uint2*>(dst)[i] = o;
}

__global__ __launch_bounds__(256) void cvt4_kernel(const float* __restrict__ s0,
    const float* __restrict__ s1, const float* __restrict__ s2, const float* __restrict__ s3,
    u16* __restrict__ d0, u16* __restrict__ d1, u16* __restrict__ d2, u16* __restrict__ d3, int n4) {
  int i = blockIdx.x * 256 + threadIdx.x;
  if (i >= n4) return;
  const float* s = (blockIdx.y == 0) ? s0 : (blockIdx.y == 1) ? s1 : (blockIdx.y == 2) ? s2 : s3;
  u16* d = (blockIdx.y == 0) ? d0 : (blockIdx.y == 1) ? d1 : (blockIdx.y == 2) ? d2 : d3;
  float4 v = reinterpret_cast<const float4*>(s)[i];
  uint2 o;
  o.x = cvtpk(v.x, v.y);
  o.y = cvtpk(v.z, v.w);
  reinterpret_cast<uint2*>(d)[i] = o;
}

// Q pre-scaled by 1/sqrt(d_k) * log2(e) so attention uses raw exp2.
#define QSCALE 0.18033688011112042f

// ---------------- old 128x128 GEMM body (kept for gemm_out) ----------------
#define BM 128
#define BN 128
#define BKK 32

template <int MODE, typename OutT>
__device__ __forceinline__ void gemm_bt_body(const u16* __restrict__ A, const u16* __restrict__ Bm,
                                             OutT* __restrict__ C, int M, int N, int K,
                                             int by, int bx, float oscale) {
  __shared__ u16 As[BM * BKK];
  __shared__ u16 Bs[BN * BKK];
  const int tid = threadIdx.x;
  const int lane = tid & 63;
  const int wave = tid >> 6;
  const int wr = wave >> 1, wc = wave & 1;
  const int l15 = lane & 15, lhi = lane >> 4;
  const int rowA0 = by * BM, colB0 = bx * BN;

  const f32x4 fzero = {0.f, 0.f, 0.f, 0.f};
  f32x4 acc[4][4];
#pragma unroll
  for (int m = 0; m < 4; ++m)
#pragma unroll
    for (int n = 0; n < 4; ++n) acc[m][n] = fzero;

  for (int k0 = 0; k0 < K; k0 += BKK) {
#pragma unroll
    for (int c = 0; c < 2; ++c) {
      const int chunk = wave * 2 + c;
      const int elem = chunk * 512 + lane * 8;
      const int r = elem >> 5;
      const int cc = elem & 31;
      const u16* gA = A + (size_t)(rowA0 + r) * K + k0 + cc;
      const u16* gB = Bm + (size_t)(colB0 + r) * K + k0 + cc;
      __builtin_amdgcn_global_load_lds((const AS1 uint32_t*)gA,
                                       (AS3 uint32_t*)(As + chunk * 512), 16, 0, 0);
      __builtin_amdgcn_global_load_lds((const AS1 uint32_t*)gB,
                                       (AS3 uint32_t*)(Bs + chunk * 512), 16, 0, 0);
    }
    __syncthreads();

    bf16x8 af[4], bfr[4];
#pragma unroll
    for (int m = 0; m < 4; ++m)
      af[m] = *reinterpret_cast<const bf16x8*>(&As[(wr * 64 + m * 16 + l15) * BKK + lhi * 8]);
#pragma unroll
    for (int n = 0; n < 4; ++n)
      bfr[n] = *reinterpret_cast<const bf16x8*>(&Bs[(wc * 64 + n * 16 + l15) * BKK + lhi * 8]);
#pragma unroll
    for (int m = 0; m < 4; ++m)
#pragma unroll
      for (int n = 0; n < 4; ++n)
        acc[m][n] = __builtin_amdgcn_mfma_f32_16x16x32_bf16(af[m], bfr[n], acc[m][n], 0, 0, 0);
    __syncthreads();
  }

#pragma unroll
  for (int m = 0; m < 4; ++m)
#pragma unroll
    for (int n = 0; n < 4; ++n) {
      const int row0 = rowA0 + wr * 64 + m * 16 + lhi * 4;
      const int col = colB0 + wc * 64 + n * 16 + l15;
      if constexpr (MODE == 2) {
        uint2 pk;
        pk.x = cvtpk(acc[m][n][0], acc[m][n][1]);
        pk.y = cvtpk(acc[m][n][2], acc[m][n][3]);
        *reinterpret_cast<uint2*>((u16*)C + (size_t)col * M + row0) = pk;
      } else if constexpr (MODE == 1) {
#pragma unroll
        for (int r = 0; r < 4; ++r)
          ((float*)C)[(size_t)(row0 + r) * N + col] = acc[m][n][r];
      } else {
#pragma unroll
        for (int r = 0; r < 4; ++r)
          ((u16*)C)[(size_t)(row0 + r) * N + col] = f2bf(acc[m][n][r] * oscale);
      }
    }
}

__global__ __launch_bounds__(256) void gemm_out_kernel(const u16* __restrict__ A,
    const u16* __restrict__ Bm, float* __restrict__ C, int M, int N, int K) {
  const int id = blockIdx.x;           // 0..511
  const int xcd = id & 7;
  const int slot = id >> 3;            // 0..63
  const int byi = slot & 7;
  const int bx = slot >> 3;            // 0..7
  const int by = xcd + 8 * byi;
  gemm_bt_body<1, float>(A, Bm, C, M, N, K, by, bx, 1.f);
}

// ---------------- 256x256 / BK=64 / 8-wave GEMM with per-phase interleaved staging ----------------
// C = A * B^T. LDS 128 KB: [buf 0/1][A 32KB | B 32KB][256 rows][64 k] bf16, XOR-swizzled
// byte ^= ((row&7)<<4). global_load_lds writes linearly -> global SOURCE address pre-swizzled.
// Wave layout 4M x 2N (wave tile 64x128): A ds-read ONLY in phase 1 (held in regs), so the
// current buffer's A region is free from phase 2 on -> tile t+2's A staged there at p2/p3.
// Next-tile B staged into the other buffer at p1/p2. vmcnt(4) once per tile at phase 4:
// drains all of tile t+1, leaves t+2's 4 A-loads in flight. Never vmcnt(0) in steady state.
#define GBK 64

template <int MODE, typename OutT>
__device__ __forceinline__ void gemm256_body(u16* __restrict__ lds,
    const u16* __restrict__ A, const u16* __restrict__ Bm, OutT* __restrict__ C,
    int M, int N, int K, int by, int bx, float oscale) {
  const int tid = threadIdx.x;
  const int lane = tid & 63;
  const int wave = tid >> 6;                 // 0..7
  const int wm = wave >> 1, wn = wave & 1;   // 4M x 2N; wave tile 64(M) x 128(N)
  const int l15 = lane & 15, lhi = lane >> 4;
  const int axor = (lane & 7) << 4;          // row&7 == l15&7 for all frag reads

  // staging: one 8KB quarter (64 rows) per gload; thread -> (row = tid>>3, slot = (tid&7)^(row&7))
  const int srow = tid >> 3;                               // 0..63 within quarter
  const int scol = (((tid & 7) ^ (srow & 7)) << 4);        // pre-swizzled source col byte
  const size_t Kb = (size_t)K * 2;
  const uint8_t* Ag = (const uint8_t*)A + (size_t)(by * 256 + srow) * Kb + scol;
  const uint8_t* Bg = (const uint8_t*)Bm + (size_t)(bx * 256 + srow) * Kb + scol;
  uint8_t* Lb = (uint8_t*)lds;  // [buf*65536 | +32768 for B][q*8192 + tid*16]

#define STG_A(bufi, kt, q)                                                                 \
  __builtin_amdgcn_global_load_lds(                                                       \
      (const AS1 uint32_t*)(Ag + (size_t)(q) * 64 * Kb + (size_t)(kt) * 128),              \
      (AS3 uint32_t*)(Lb + (bufi) * 65536 + (q) * 8192 + tid * 16), 16, 0, 0)

#define STG_B(bufi, kt, q)                                                                 \
  __builtin_amdgcn_global_load_lds(                                                       \
      (const AS1 uint32_t*)(Bg + (size_t)(q) * 64 * Kb + (size_t)(kt) * 128),              \
      (AS3 uint32_t*)(Lb + (bufi) * 65536 + 32768 + (q) * 8192 + tid * 16), 16, 0, 0)

#define RD_A()                                                                             \
  do {                                                                                     \
    _Pragma("unroll") for (int mm = 0; mm < 4; ++mm)                                       \
      _Pragma("unroll") for (int ks = 0; ks < 2; ++ks)                                     \
        aF[mm][ks] = *reinterpret_cast<const bf16x8*>(                                     \
            Ab + (wm * 64 + mm * 16 + l15) * 128 + ((ks * 64 + lhi * 16) ^ axor));         \
  } while (0)

#define RD_B(nh)                                                                           \
  do {                                                                                     \
    _Pragma("unroll") for (int nn = 0; nn < 2; ++nn)                                       \
      _Pragma("unroll") for (int ks = 0; ks < 2; ++ks)                                     \
        bF[nn][ks] = *reinterpret_cast<const bf16x8*>(                                     \
            Bb + (wn * 128 + (nh) * 32 + nn * 16 + l15) * 128 +                            \
                 ((ks * 64 + lhi * 16) ^ axor));                                           \
  } while (0)

#define MFMA_P(nh)                                                                         \
  do {                                                                                     \
    asm volatile("s_waitcnt lgkmcnt(0)" ::: "memory");                                     \
    __builtin_amdgcn_sched_barrier(0);                                                     \
    __builtin_amdgcn_s_setprio(1);                                                         \
    _Pragma("unroll") for (int mm = 0; mm < 4; ++mm)                                       \
      _Pragma("unroll") for (int nn = 0; nn < 2; ++nn)                                     \
        _Pragma("unroll") for (int ks = 0; ks < 2; ++ks)                                   \
          acc[mm][(nh) * 2 + nn] = __builtin_amdgcn_mfma_f32_16x16x32_bf16(                \
              aF[mm][ks], bF[nn][ks], acc[mm][(nh) * 2 + nn], 0, 0, 0);                    \
    __builtin_amdgcn_s_setprio(0);                                                         \
  } while (0)

  const f32x4 fzero = {0.f, 0.f, 0.f, 0.f};
  f32x4 acc[4][8];
#pragma unroll
  for (int m = 0; m < 4; ++m)
#pragma unroll
    for (int n = 0; n < 8; ++n) acc[m][n] = fzero;

  const int NT = K / GBK;  // 16 here (NT >= 2 assumed)

  // prologue: tile0 A+B fully, tile1 A; drain tile0 (leave tile1's 4 A-loads in flight)
#pragma unroll
  for (int q = 0; q < 4; ++q) STG_A(0, 0, q);
#pragma unroll
  for (int q = 0; q < 4; ++q) STG_B(0, 0, q);
#pragma unroll
  for (int q = 0; q < 4; ++q) STG_A(1, 1, q);
  asm volatile("s_waitcnt vmcnt(4)" ::: "memory");
  __builtin_amdgcn_s_barrier();

  bf16x8 aF[4][2], bF[2][2];
  for (int t = 0; t < NT; ++t) {
    const int pb = t & 1;
    const int nb = pb ^ 1;
    const uint8_t* Ab = Lb + pb * 65536;
    const uint8_t* Bb = Ab + 32768;

    // ---- phase 1: A frags (only LDS read of A this tile) + B(nh0); stage t+1.B q0,q1 ----
    RD_A(); RD_B(0);
    if (t + 1 < NT) { STG_B(nb, t + 1, 0); STG_B(nb, t + 1, 1); }
    asm volatile("s_waitcnt lgkmcnt(8)" ::: "memory");
    __builtin_amdgcn_s_barrier();
    MFMA_P(0);
    __builtin_amdgcn_s_barrier();   // all waves' A reads serviced -> pb.A region free

    // ---- phase 2: B(nh1); stage t+1.B q2,q3 + t+2.A q0,q1 (into pb.A, now free) ----
    RD_B(1);
    if (t + 1 < NT) { STG_B(nb, t + 1, 2); STG_B(nb, t + 1, 3); }
    if (t + 2 < NT) { STG_A(pb, t + 2, 0); STG_A(pb, t + 2, 1); }
    __builtin_amdgcn_s_barrier();
    MFMA_P(1);
    __builtin_amdgcn_s_barrier();

    // ---- phase 3: B(nh2); stage t+2.A q2,q3 ----
    RD_B(2);
    if (t + 2 < NT) { STG_A(pb, t + 2, 2); STG_A(pb, t + 2, 3); }
    __builtin_amdgcn_s_barrier();
    MFMA_P(2);
    __builtin_amdgcn_s_barrier();

    // ---- phase 4: B(nh3); counted drain: t+1 fully resident, t+2.A stays in flight ----
    RD_B(3);
    __builtin_amdgcn_s_barrier();
    MFMA_P(3);
    if (t + 1 < NT) {
      if (t + 2 < NT) {
        asm volatile("s_waitcnt vmcnt(4)" ::: "memory");
      } else {
        asm volatile("s_waitcnt vmcnt(0)" ::: "memory");
      }
    }
    __builtin_amdgcn_s_barrier();
  }

  // ---- epilogue ----
#pragma unroll
  for (int mf = 0; mf < 4; ++mf)
#pragma unroll
    for (int nf = 0; nf < 8; ++nf) {
      const int row0 = by * 256 + wm * 64 + mf * 16 + lhi * 4;
      const int col = bx * 256 + wn * 128 + nf * 16 + l15;
      if constexpr (MODE == 2) {
        uint2 pk;
        pk.x = cvtpk(acc[mf][nf][0], acc[mf][nf][1]);
        pk.y = cvtpk(acc[mf][nf][2], acc[mf][nf][3]);
        *reinterpret_cast<uint2*>((u16*)C + (size_t)col * M + row0) = pk;
      } else if constexpr (MODE == 1) {
#pragma unroll
        for (int r = 0; r < 4; ++r)
          ((float*)C)[(size_t)(row0 + r) * N + col] = acc[mf][nf][r];
      } else {
#pragma unroll
        for (int r = 0; r < 4; ++r)
          ((u16*)C)[(size_t)(row0 + r) * N + col] = f2bf(acc[mf][nf][r] * oscale);
      }
    }
#undef STG_A
#undef STG_B
#undef RD_A
#undef RD_B
#undef MFMA_P
}

// XCD-aware: id%8 = XCD; per XCD, 12 consecutive slots (4bx x 3bz) share one A-row
// panel (512 KB) so it stays L2-resident. 384 = 8 xcd x 4 byi x 4 bx x 3 bz.
__global__ __launch_bounds__(512, 2) void gemm_qkv_kernel(const u16* __restrict__ A,
    const u16* __restrict__ W0, const u16* __restrict__ W1, const u16* __restrict__ W2,
    u16* __restrict__ OQ, u16* __restrict__ OK, u16* __restrict__ OVT, int M, int N, int K) {
  __shared__ u16 lds[2][2][256 * GBK];  // 128 KB
  const int id = blockIdx.x;            // 0..383
  const int xcd = id & 7;
  const int slot = id >> 3;             // 0..47
  const int byi = slot / 12;            // 0..3
  const int c = slot - byi * 12;        // 0..11
  const int bx = c & 3;
  const int bz = c >> 2;                // 0..2
  const int by = xcd + 8 * byi;         // 0..31
  if (bz == 0)      gemm256_body<0, u16>(&lds[0][0][0], A, W0, OQ,  M, N, K, by, bx, QSCALE);
  else if (bz == 1) gemm256_body<0, u16>(&lds[0][0][0], A, W1, OK,  M, N, K, by, bx, 1.f);
  else              gemm256_body<2, u16>(&lds[0][0][0], A, W2, OVT, M, N, K, by, bx, 1.f);
}

// ---------------- causal flash attention v6: 32x32 MFMA, in-register P ----------------
#define KVB 64

__global__ __launch_bounds__(512, 4) void attn_kernel(const u16* __restrict__ Q,
    const u16* __restrict__ Kg, const u16* __restrict__ VTg, u16* __restrict__ O,
    int S, int H, int Dm, int T) {
  const int bh = blockIdx.x;
  const int b = bh / H, h = bh % H;
  const int by = blockIdx.y;
  const int y = (by < 4) ? (7 - by) : (by - 4);
  const int qH = 1024 + y * 128;
  const int qL = 896 - y * 128;
  const int tid = threadIdx.x;
  const int lane = tid & 63, wave = tid >> 6;
  const int l31 = lane & 31, hi = lane >> 5;

  __shared__ u16 KVs[2][2][64 * 64];  // [buf][K=0/V=1], col-block swizzle ^((row&7)<<3)  (32KB)

  const u16* Qh = Q + ((size_t)b * S) * Dm + h * 64;
  const u16* Kh = Kg + ((size_t)b * S) * Dm + h * 64;
  const u16* Vh = VTg + (size_t)(h * 64) * T + (size_t)b * S;
  const int qv = (wave < 4) ? (qH + wave * 32) : (qL + (wave - 4) * 32);
  const int qr = qv + l31;

  // Q frags (B-operand 32x32x16): col = q = l31, k = dc*16 + hi*8 + j
  bf16x8 qf[4];
#pragma unroll
  for (int dc = 0; dc < 4; ++dc)
    qf[dc] = *reinterpret_cast<const bf16x8*>(Qh + (size_t)qr * Dm + dc * 16 + hi * 8);

  f32x16 acc[2];  // O^T: d = db*32 + (reg&3)+8*(reg>>2)+4*hi, q = l31
#pragma unroll
  for (int db = 0; db < 2; ++db)
#pragma unroll
    for (int r = 0; r < 16; ++r) acc[db][r] = 0.f;
  float mrow = -1e30f, lrow = 0.f;

#define STAGE(bufi, kvoff)                                                                     \
  do {                                                                                         \
    const int srow = tid >> 3;                                                                 \
    const int scol = (((tid & 7) ^ (srow & 7)) << 3);                                          \
    __builtin_amdgcn_global_load_lds(                                                          \
        (const AS1 uint32_t*)(Kh + (size_t)((kvoff) + srow) * Dm + scol),                      \
        (AS3 uint32_t*)(&KVs[bufi][0][tid * 8]), 16, 0, 0);                                    \
    __builtin_amdgcn_global_load_lds(                                                          \
        (const AS1 uint32_t*)(Vh + (size_t)srow * T + (kvoff) + scol),                         \
        (AS3 uint32_t*)(&KVs[bufi][1][tid * 8]), 16, 0, 0);                                    \
  } while (0)

  const int nt = qH / 64 + 2;
  STAGE(0, 0);
  int buf = 0;

  for (int t = 0; t < nt; ++t) {
    __syncthreads();
    const int kv = t * KVB;
    if (t + 1 < nt) STAGE(buf ^ 1, (t + 1) * KVB);

    if (kv <= qv + 31) {
      const u16* KB = KVs[buf][0];
      const u16* VB = KVs[buf][1];

      // ---- QK^T: sc[b] covers kv rows b*32..b*32+31, q = l31 ----
      f32x16 sc[2];
#pragma unroll
      for (int bb = 0; bb < 2; ++bb) {
#pragma unroll
        for (int r = 0; r < 16; ++r) sc[bb][r] = 0.f;
#pragma unroll
        for (int dc = 0; dc < 4; ++dc) {
          const bf16x8 kf = *reinterpret_cast<const bf16x8*>(
              KB + (bb * 32 + l31) * 64 + (((dc * 2 + hi) ^ (l31 & 7)) << 3));
          sc[bb] = __builtin_amdgcn_mfma_f32_32x32x16_bf16(kf, qf[dc], sc[bb], 0, 0, 0);
        }
      }

      // ---- causal mask + row max (31 in-reg fmax + 1 shfl) ----
      const bool msk = (kv + KVB - 1 > qv);
      float bmax = -3e38f;
#pragma unroll
      for (int bb = 0; bb < 2; ++bb)
#pragma unroll
        for (int r = 0; r < 16; ++r) {
          float v = sc[bb][r];
          if (msk) {
            const int kvg = kv + bb * 32 + (r & 3) + 8 * (r >> 2) + 4 * hi;
            v = (kvg > qr) ? -1e30f : v;
            sc[bb][r] = v;
          }
          bmax = fmaxf(bmax, v);
        }
      bmax = fmaxf(bmax, __shfl_xor(bmax, 32, 64));

      // ---- defer-max rescale ----
      if (!__all(bmax <= mrow + 6.f)) {
        const float mn = fmaxf(mrow, bmax);
        const float fac = __builtin_amdgcn_exp2f(mrow - mn);
        mrow = mn;
        lrow *= fac;
#pragma unroll
        for (int db = 0; db < 2; ++db)
#pragma unroll
          for (int r = 0; r < 16; ++r) acc[db][r] *= fac;
      }

      // ---- exp2 + per-lane partial sum ----
      float rs = 0.f;
#pragma unroll
      for (int bb = 0; bb < 2; ++bb)
#pragma unroll
        for (int r = 0; r < 16; ++r) {
          const float p = __builtin_amdgcn_exp2f(sc[bb][r] - mrow);
          sc[bb][r] = p;
          rs += p;
        }
      lrow += rs;

      // ---- PV: per 16-kv chunk, build P B-frag in regs via cvt_pk + permlane32_swap ----
#pragma unroll
      for (int cc = 0; cc < 4; ++cc) {
        const int bb = cc >> 1, c2 = cc & 1;
        uint32_t a0 = cvtpk(sc[bb][8 * c2 + 0], sc[bb][8 * c2 + 1]);
        uint32_t a1 = cvtpk(sc[bb][8 * c2 + 2], sc[bb][8 * c2 + 3]);
        uint32_t b0 = cvtpk(sc[bb][8 * c2 + 4], sc[bb][8 * c2 + 5]);
        uint32_t b1 = cvtpk(sc[bb][8 * c2 + 6], sc[bb][8 * c2 + 7]);
        asm("v_permlane32_swap_b32 %0, %1" : "+v"(a0), "+v"(b0));
        asm("v_permlane32_swap_b32 %0, %1" : "+v"(a1), "+v"(b1));
        union { uint32_t u[4]; bf16x8 v8; } pf;
        pf.u[0] = a0; pf.u[1] = a1; pf.u[2] = b0; pf.u[3] = b1;
#pragma unroll
        for (int db = 0; db < 2; ++db) {
          const bf16x8 vfg = *reinterpret_cast<const bf16x8*>(
              VB + (db * 32 + l31) * 64 + (((cc * 2 + hi) ^ (l31 & 7)) << 3));
          acc[db] = __builtin_amdgcn_mfma_f32_32x32x16_bf16(vfg, pf.v8, acc[db], 0, 0, 0);
        }
      }
    }
    buf ^= 1;
  }

  // ---- epilogue: finish l, O^T regs -> LDS (row-swizzled) -> coalesced 16B stores ----
  lrow += __shfl_xor(lrow, 32, 64);
  const float inv = 1.f / lrow;
  __syncthreads();
  u16* Ost = &KVs[0][0][0];  // 32 KB = [256 rows][64 d], 8-elem col-blocks swizzled by row&7
  {
    const int row = wave * 32 + l31;
#pragma unroll
    for (int db = 0; db < 2; ++db)
#pragma unroll
      for (int g = 0; g < 4; ++g) {
        uint2 pk;
        pk.x = cvtpk(acc[db][4 * g + 0] * inv, acc[db][4 * g + 1] * inv);
        pk.y = cvtpk(acc[db][4 * g + 2] * inv, acc[db][4 * g + 3] * inv);
        const int blk = 4 * db + g;  // d = db*32 + 8g + 4hi + 0..3
        const int addr = row * 64 + (((blk ^ (row & 7)) << 3)) + 4 * hi;
        *reinterpret_cast<uint2*>(Ost + addr) = pk;
      }
  }
  __syncthreads();
#pragma unroll
  for (int p = 0; p < 4; ++p) {
    const int idx = p * 512 + tid;
    const int row = idx >> 3, seg = idx & 7;
    const float4 v = *reinterpret_cast<const float4*>(Ost + row * 64 + ((seg ^ (row & 7)) << 3));
    const int q = (row < 128) ? (qH + row) : (qL + row - 128);
    *reinterpret_cast<float4*>(O + ((size_t)b * S + q) * Dm + h * 64 + seg * 8) = v;
  }
#undef STAGE
}

// ---------------- launch ----------------
extern "C" void kernel_launch(void* const* d_in, const int* in_sizes, int n_in,
                              void* d_out, int out_size, void* d_ws, size_t ws_size,
                              hipStream_t stream) {
  const float* x  = (const float*)d_in[0];
  const float* Wq = (const float*)d_in[1];
  const float* Wk = (const float*)d_in[2];
  const float* Wv = (const float*)d_in[3];
  const float* Wo = (const float*)d_in[4];
  float* out = (float*)d_out;

  const int B = 4, S = 2048, D = 1024, H = 16;
  const int T = B * S;  // 8192

  uint8_t* p = (uint8_t*)d_ws;
  u16* xb  = (u16*)p; p += (size_t)T * D * 2;
  u16* wqb = (u16*)p; p += (size_t)D * D * 2;
  u16* wkb = (u16*)p; p += (size_t)D * D * 2;
  u16* wvb = (u16*)p; p += (size_t)D * D * 2;
  u16* wob = (u16*)p; p += (size_t)D * D * 2;
  u16* Qb  = (u16*)p; p += (size_t)T * D * 2;
  u16* Kb  = (u16*)p; p += (size_t)T * D * 2;
  u16* VTb = (u16*)p; p += (size_t)D * T * 2;  // V^T [D][T]
  u16* Ab  = xb;  // xb dead after QKV gemm -> reuse for attn output

  cvt_kernel<<<dim3(T * D / 4 / 256), dim3(256), 0, stream>>>(x, xb, T * D / 4);
  cvt4_kernel<<<dim3(D * D / 4 / 256, 4), dim3(256), 0, stream>>>(
      Wq, Wk, Wv, Wo, wqb, wkb, wvb, wob, D * D / 4);

  // 256^2 interleaved-staging QKV: 32 Mtiles x 4 Ntiles x 3 GEMMs = 384 blocks of 512
  gemm_qkv_kernel<<<dim3(384), dim3(512), 0, stream>>>(xb, wqb, wkb, wvb, Qb, Kb, VTb, T, D, D);

  // grid: x = bh (XCD locality), y = 8 paired q-range blocks
  attn_kernel<<<dim3(B * H, 8), dim3(512), 0, stream>>>(Qb, Kb, VTb, Ab, S, H, D, T);

  gemm_out_kernel<<<dim3(512), dim3(256), 0, stream>>>(Ab, wob, out, T, D, D);
}

// Round 3
// 145.710 us; speedup vs baseline: 1.2508x; 1.2192x over previous
//
#include <hip/hip_runtime.h>
#include <hip/hip_bf16.h>
#include <stdint.h>

typedef unsigned short u16;
typedef __attribute__((ext_vector_type(8))) short bf16x8;
typedef __attribute__((ext_vector_type(4))) float f32x4;
typedef __attribute__((ext_vector_type(16))) float f32x16;

#define AS1 __attribute__((address_space(1)))
#define AS3 __attribute__((address_space(3)))

__device__ __forceinline__ u16 f2bf(float f) {
  union { float f; uint32_t u; } v; v.f = f;
  uint32_t u = v.u;
  return (u16)((u + 0x7FFFu + ((u >> 16) & 1u)) >> 16);
}

// packed f32x2 -> bf16x2 (RNE), single instruction
__device__ __forceinline__ uint32_t cvtpk(float lo, float hi) {
  uint32_t d;
  asm("v_cvt_pk_bf16_f32 %0, %1, %2" : "=v"(d) : "v"(lo), "v"(hi));
  return d;
}

// ---------------- fp32 -> bf16 convert (single launch for x + 4 weights) ----------------
// blocks 0..8191: x (8192*1024 elems). blocks 8192..12287: weights, 1024 blocks each.
__global__ __launch_bounds__(256) void cvt_all_kernel(const float* __restrict__ x,
    const float* __restrict__ Wq, const float* __restrict__ Wk,
    const float* __restrict__ Wv, const float* __restrict__ Wo,
    u16* __restrict__ xb, u16* __restrict__ wqb, u16* __restrict__ wkb,
    u16* __restrict__ wvb, u16* __restrict__ wob) {
  const int bid = blockIdx.x;
  const float* s;
  u16* d;
  int i;
  if (bid < 8192) {
    s = x; d = xb; i = bid * 256 + threadIdx.x;
  } else {
    const int w = (bid - 8192) >> 10;
    i = ((bid - 8192) & 1023) * 256 + threadIdx.x;
    s = (w == 0) ? Wq : (w == 1) ? Wk : (w == 2) ? Wv : Wo;
    d = (w == 0) ? wqb : (w == 1) ? wkb : (w == 2) ? wvb : wob;
  }
  float4 v = reinterpret_cast<const float4*>(s)[i];
  uint2 o;
  o.x = cvtpk(v.x, v.y);
  o.y = cvtpk(v.z, v.w);
  reinterpret_cast<uint2*>(d)[i] = o;
}

// Q pre-scaled by 1/sqrt(d_k) * log2(e) so attention uses raw exp2.
#define QSCALE 0.18033688011112042f

// ---------------- 128x128 / BK=64 double-buffered GEMM, 2 blocks/CU ----------------
// C = A * B^T. 4 waves (wave tile 64x64). LDS 64 KB: [buf][A|B][128 rows][64 k] bf16,
// XOR-swizzled 16B slots: slot ^= (row&7). global_load_lds writes linearly -> global
// SOURCE col pre-swizzled with the same involution; ds_read applies it on read.
// One __syncthreads per K-step (compiler emits vmcnt(0)+lgkmcnt(0) drain there).
// Latency hiding comes from the co-resident 2nd block (TLP, m103/m114 mechanism).
// K is a template constant -> full unroll, imm-folded addressing (no per-step VALU).
#define GK 64

template <int MODE, int KC, typename OutT>
__device__ __forceinline__ void gemm128_body(u16* __restrict__ lds,
    const u16* __restrict__ A, const u16* __restrict__ Bm, OutT* __restrict__ C,
    int M, int N, int by, int bx, float oscale) {
  const int tid = threadIdx.x;            // 0..255
  const int lane = tid & 63;
  const int wave = tid >> 6;              // 0..3
  const int wm = wave >> 1, wn = wave & 1;  // 2M x 2N; wave tile 64x64
  const int l15 = lane & 15, lhi = lane >> 4;
  const int axor = (lane & 7) << 4;       // row&7 == lane&7 for all frag reads

  // staging: one gload = 256 thr x 16B = 4KB = 32 rows; thread -> (row=tid>>3, slot=(tid&7)^(row&7))
  const int srow = tid >> 3;                          // 0..31
  const int scol = (((tid & 7) ^ (srow & 7)) << 4);   // pre-swizzled source col byte
  const size_t Kb = (size_t)KC * 2;
  const uint8_t* Ag = (const uint8_t*)A + (size_t)(by * 128 + srow) * Kb + scol;
  const uint8_t* Bg = (const uint8_t*)Bm + (size_t)(bx * 128 + srow) * Kb + scol;
  uint8_t* Lb = (uint8_t*)lds;  // [buf*32768 | +16384 for B][c*4096 + tid*16]

#define STG128(bufi, kt)                                                                  \
  do {                                                                                    \
    _Pragma("unroll") for (int c = 0; c < 4; ++c) {                                       \
      __builtin_amdgcn_global_load_lds(                                                   \
          (const AS1 uint32_t*)(Ag + (size_t)c * 32 * Kb + (size_t)(kt) * 128),           \
          (AS3 uint32_t*)(Lb + (bufi) * 32768 + c * 4096 + tid * 16), 16, 0, 0);          \
      __builtin_amdgcn_global_load_lds(                                                   \
          (const AS1 uint32_t*)(Bg + (size_t)c * 32 * Kb + (size_t)(kt) * 128),           \
          (AS3 uint32_t*)(Lb + (bufi) * 32768 + 16384 + c * 4096 + tid * 16), 16, 0, 0);  \
    }                                                                                     \
  } while (0)

  const f32x4 fzero = {0.f, 0.f, 0.f, 0.f};
  f32x4 acc[4][4];
#pragma unroll
  for (int m = 0; m < 4; ++m)
#pragma unroll
    for (int n = 0; n < 4; ++n) acc[m][n] = fzero;

  constexpr int NT = KC / GK;  // 16

  STG128(0, 0);
  __syncthreads();

#pragma unroll
  for (int t = 0; t < NT; ++t) {
    const int cur = t & 1;
    if (t + 1 < NT) STG128(cur ^ 1, t + 1);  // prefetch next tile into other buffer
    const uint8_t* Ab = Lb + cur * 32768;
    const uint8_t* Bb = Ab + 16384;
    bf16x8 aF[4][2], bF[4][2];
#pragma unroll
    for (int ff = 0; ff < 4; ++ff)
#pragma unroll
      for (int ks = 0; ks < 2; ++ks) {
        aF[ff][ks] = *reinterpret_cast<const bf16x8*>(
            Ab + (wm * 64 + ff * 16 + l15) * 128 + ((ks * 64 + lhi * 16) ^ axor));
        bF[ff][ks] = *reinterpret_cast<const bf16x8*>(
            Bb + (wn * 64 + ff * 16 + l15) * 128 + ((ks * 64 + lhi * 16) ^ axor));
      }
    __builtin_amdgcn_s_setprio(1);
#pragma unroll
    for (int mm = 0; mm < 4; ++mm)
#pragma unroll
      for (int nn = 0; nn < 4; ++nn)
#pragma unroll
        for (int ks = 0; ks < 2; ++ks)
          acc[mm][nn] = __builtin_amdgcn_mfma_f32_16x16x32_bf16(aF[mm][ks], bF[nn][ks],
                                                                acc[mm][nn], 0, 0, 0);
    __builtin_amdgcn_s_setprio(0);
    __syncthreads();  // drains this step's gloads (vmcnt 0) + orders buffer reuse
  }

  // ---- epilogue ----
#pragma unroll
  for (int mf = 0; mf < 4; ++mf)
#pragma unroll
    for (int nf = 0; nf < 4; ++nf) {
      const int row0 = by * 128 + wm * 64 + mf * 16 + lhi * 4;
      const int col = bx * 128 + wn * 64 + nf * 16 + l15;
      if constexpr (MODE == 2) {
        uint2 pk;
        pk.x = cvtpk(acc[mf][nf][0], acc[mf][nf][1]);
        pk.y = cvtpk(acc[mf][nf][2], acc[mf][nf][3]);
        *reinterpret_cast<uint2*>((u16*)C + (size_t)col * M + row0) = pk;
      } else if constexpr (MODE == 1) {
#pragma unroll
        for (int r = 0; r < 4; ++r)
          ((float*)C)[(size_t)(row0 + r) * N + col] = acc[mf][nf][r];
      } else {
#pragma unroll
        for (int r = 0; r < 4; ++r)
          ((u16*)C)[(size_t)(row0 + r) * N + col] = f2bf(acc[mf][nf][r] * oscale);
      }
    }
#undef STG128
}

// Grid 1536 = 8 xcd x 3 bz x 8 byi x 8 bx; 3 exact rounds at 2 blocks/CU.
// Per XCD: 64-slot stretch = one GEMM (its 2MB W stays L2-resident) x 8 A-panels
// (8 x 256KB = 2MB) -> ~4MB working set fits the 4MB XCD L2.
__global__ __launch_bounds__(256, 2) void gemm_qkv_kernel(const u16* __restrict__ A,
    const u16* __restrict__ W0, const u16* __restrict__ W1, const u16* __restrict__ W2,
    u16* __restrict__ OQ, u16* __restrict__ OK, u16* __restrict__ OVT, int M, int N) {
  __shared__ u16 lds[2][2][128 * GK];  // 64 KB
  const int id = blockIdx.x;           // 0..1535
  const int xcd = id & 7;
  const int slot = id >> 3;            // 0..191
  const int bz = slot >> 6;            // 0..2
  const int r = slot & 63;
  const int byi = r >> 3, bx = r & 7;
  const int by = xcd + 8 * byi;        // 0..63
  if (bz == 0)      gemm128_body<0, 1024, u16>(&lds[0][0][0], A, W0, OQ,  M, N, by, bx, QSCALE);
  else if (bz == 1) gemm128_body<0, 1024, u16>(&lds[0][0][0], A, W1, OK,  M, N, by, bx, 1.f);
  else              gemm128_body<2, 1024, u16>(&lds[0][0][0], A, W2, OVT, M, N, by, bx, 1.f);
}

// 512 blocks = 1 exact round at 2 blocks/CU.
__global__ __launch_bounds__(256, 2) void gemm_out_kernel(const u16* __restrict__ A,
    const u16* __restrict__ Bm, float* __restrict__ C, int M, int N) {
  __shared__ u16 lds[2][2][128 * GK];  // 64 KB
  const int id = blockIdx.x;           // 0..511
  const int xcd = id & 7;
  const int slot = id >> 3;            // 0..63
  const int byi = slot >> 3, bx = slot & 7;
  const int by = xcd + 8 * byi;
  gemm128_body<1, 1024, float>(&lds[0][0][0], A, Bm, C, M, N, by, bx, 1.f);
}

// ---------------- causal flash attention v6: 32x32 MFMA, in-register P ----------------
#define KVB 64

__global__ __launch_bounds__(512, 4) void attn_kernel(const u16* __restrict__ Q,
    const u16* __restrict__ Kg, const u16* __restrict__ VTg, u16* __restrict__ O,
    int S, int H, int Dm, int T) {
  const int bh = blockIdx.x;
  const int b = bh / H, h = bh % H;
  const int by = blockIdx.y;
  const int y = (by < 4) ? (7 - by) : (by - 4);
  const int qH = 1024 + y * 128;
  const int qL = 896 - y * 128;
  const int tid = threadIdx.x;
  const int lane = tid & 63, wave = tid >> 6;
  const int l31 = lane & 31, hi = lane >> 5;

  __shared__ u16 KVs[2][2][64 * 64];  // [buf][K=0/V=1], col-block swizzle ^((row&7)<<3)  (32KB)

  const u16* Qh = Q + ((size_t)b * S) * Dm + h * 64;
  const u16* Kh = Kg + ((size_t)b * S) * Dm + h * 64;
  const u16* Vh = VTg + (size_t)(h * 64) * T + (size_t)b * S;
  const int qv = (wave < 4) ? (qH + wave * 32) : (qL + (wave - 4) * 32);
  const int qr = qv + l31;

  // Q frags (B-operand 32x32x16): col = q = l31, k = dc*16 + hi*8 + j
  bf16x8 qf[4];
#pragma unroll
  for (int dc = 0; dc < 4; ++dc)
    qf[dc] = *reinterpret_cast<const bf16x8*>(Qh + (size_t)qr * Dm + dc * 16 + hi * 8);

  f32x16 acc[2];  // O^T: d = db*32 + (reg&3)+8*(reg>>2)+4*hi, q = l31
#pragma unroll
  for (int db = 0; db < 2; ++db)
#pragma unroll
    for (int r = 0; r < 16; ++r) acc[db][r] = 0.f;
  float mrow = -1e30f, lrow = 0.f;

#define STAGE(bufi, kvoff)                                                                     \
  do {                                                                                         \
    const int srow = tid >> 3;                                                                 \
    const int scol = (((tid & 7) ^ (srow & 7)) << 3);                                          \
    __builtin_amdgcn_global_load_lds(                                                          \
        (const AS1 uint32_t*)(Kh + (size_t)((kvoff) + srow) * Dm + scol),                      \
        (AS3 uint32_t*)(&KVs[bufi][0][tid * 8]), 16, 0, 0);                                    \
    __builtin_amdgcn_global_load_lds(                                                          \
        (const AS1 uint32_t*)(Vh + (size_t)srow * T + (kvoff) + scol),                         \
        (AS3 uint32_t*)(&KVs[bufi][1][tid * 8]), 16, 0, 0);                                    \
  } while (0)

  const int nt = qH / 64 + 2;
  STAGE(0, 0);
  int buf = 0;

  for (int t = 0; t < nt; ++t) {
    __syncthreads();
    const int kv = t * KVB;
    if (t + 1 < nt) STAGE(buf ^ 1, (t + 1) * KVB);

    if (kv <= qv + 31) {
      const u16* KB = KVs[buf][0];
      const u16* VB = KVs[buf][1];

      // ---- QK^T: sc[b] covers kv rows b*32..b*32+31, q = l31 ----
      f32x16 sc[2];
#pragma unroll
      for (int bb = 0; bb < 2; ++bb) {
#pragma unroll
        for (int r = 0; r < 16; ++r) sc[bb][r] = 0.f;
#pragma unroll
        for (int dc = 0; dc < 4; ++dc) {
          const bf16x8 kf = *reinterpret_cast<const bf16x8*>(
              KB + (bb * 32 + l31) * 64 + (((dc * 2 + hi) ^ (l31 & 7)) << 3));
          sc[bb] = __builtin_amdgcn_mfma_f32_32x32x16_bf16(kf, qf[dc], sc[bb], 0, 0, 0);
        }
      }

      // ---- causal mask + row max (31 in-reg fmax + 1 shfl) ----
      const bool msk = (kv + KVB - 1 > qv);
      float bmax = -3e38f;
#pragma unroll
      for (int bb = 0; bb < 2; ++bb)
#pragma unroll
        for (int r = 0; r < 16; ++r) {
          float v = sc[bb][r];
          if (msk) {
            const int kvg = kv + bb * 32 + (r & 3) + 8 * (r >> 2) + 4 * hi;
            v = (kvg > qr) ? -1e30f : v;
            sc[bb][r] = v;
          }
          bmax = fmaxf(bmax, v);
        }
      bmax = fmaxf(bmax, __shfl_xor(bmax, 32, 64));

      // ---- defer-max rescale ----
      if (!__all(bmax <= mrow + 6.f)) {
        const float mn = fmaxf(mrow, bmax);
        const float fac = __builtin_amdgcn_exp2f(mrow - mn);
        mrow = mn;
        lrow *= fac;
#pragma unroll
        for (int db = 0; db < 2; ++db)
#pragma unroll
          for (int r = 0; r < 16; ++r) acc[db][r] *= fac;
      }

      // ---- exp2 + per-lane partial sum ----
      float rs = 0.f;
#pragma unroll
      for (int bb = 0; bb < 2; ++bb)
#pragma unroll
        for (int r = 0; r < 16; ++r) {
          const float p = __builtin_amdgcn_exp2f(sc[bb][r] - mrow);
          sc[bb][r] = p;
          rs += p;
        }
      lrow += rs;

      // ---- PV: per 16-kv chunk, build P B-frag in regs via cvt_pk + permlane32_swap ----
#pragma unroll
      for (int cc = 0; cc < 4; ++cc) {
        const int bb = cc >> 1, c2 = cc & 1;
        uint32_t a0 = cvtpk(sc[bb][8 * c2 + 0], sc[bb][8 * c2 + 1]);
        uint32_t a1 = cvtpk(sc[bb][8 * c2 + 2], sc[bb][8 * c2 + 3]);
        uint32_t b0 = cvtpk(sc[bb][8 * c2 + 4], sc[bb][8 * c2 + 5]);
        uint32_t b1 = cvtpk(sc[bb][8 * c2 + 6], sc[bb][8 * c2 + 7]);
        asm("v_permlane32_swap_b32 %0, %1" : "+v"(a0), "+v"(b0));
        asm("v_permlane32_swap_b32 %0, %1" : "+v"(a1), "+v"(b1));
        union { uint32_t u[4]; bf16x8 v8; } pf;
        pf.u[0] = a0; pf.u[1] = a1; pf.u[2] = b0; pf.u[3] = b1;
#pragma unroll
        for (int db = 0; db < 2; ++db) {
          const bf16x8 vfg = *reinterpret_cast<const bf16x8*>(
              VB + (db * 32 + l31) * 64 + (((cc * 2 + hi) ^ (l31 & 7)) << 3));
          acc[db] = __builtin_amdgcn_mfma_f32_32x32x16_bf16(vfg, pf.v8, acc[db], 0, 0, 0);
        }
      }
    }
    buf ^= 1;
  }

  // ---- epilogue: finish l, O^T regs -> LDS (row-swizzled) -> coalesced 16B stores ----
  lrow += __shfl_xor(lrow, 32, 64);
  const float inv = 1.f / lrow;
  __syncthreads();
  u16* Ost = &KVs[0][0][0];  // 32 KB = [256 rows][64 d], 8-elem col-blocks swizzled by row&7
  {
    const int row = wave * 32 + l31;
#pragma unroll
    for (int db = 0; db < 2; ++db)
#pragma unroll
      for (int g = 0; g < 4; ++g) {
        uint2 pk;
        pk.x = cvtpk(acc[db][4 * g + 0] * inv, acc[db][4 * g + 1] * inv);
        pk.y = cvtpk(acc[db][4 * g + 2] * inv, acc[db][4 * g + 3] * inv);
        const int blk = 4 * db + g;  // d = db*32 + 8g + 4hi + 0..3
        const int addr = row * 64 + (((blk ^ (row & 7)) << 3)) + 4 * hi;
        *reinterpret_cast<uint2*>(Ost + addr) = pk;
      }
  }
  __syncthreads();
#pragma unroll
  for (int p = 0; p < 4; ++p) {
    const int idx = p * 512 + tid;
    const int row = idx >> 3, seg = idx & 7;
    const float4 v = *reinterpret_cast<const float4*>(Ost + row * 64 + ((seg ^ (row & 7)) << 3));
    const int q = (row < 128) ? (qH + row) : (qL + row - 128);
    *reinterpret_cast<float4*>(O + ((size_t)b * S + q) * Dm + h * 64 + seg * 8) = v;
  }
#undef STAGE
}

// ---------------- launch ----------------
extern "C" void kernel_launch(void* const* d_in, const int* in_sizes, int n_in,
                              void* d_out, int out_size, void* d_ws, size_t ws_size,
                              hipStream_t stream) {
  const float* x  = (const float*)d_in[0];
  const float* Wq = (const float*)d_in[1];
  const float* Wk = (const float*)d_in[2];
  const float* Wv = (const float*)d_in[3];
  const float* Wo = (const float*)d_in[4];
  float* out = (float*)d_out;

  const int B = 4, S = 2048, D = 1024, H = 16;
  const int T = B * S;  // 8192

  uint8_t* p = (uint8_t*)d_ws;
  u16* xb  = (u16*)p; p += (size_t)T * D * 2;
  u16* wqb = (u16*)p; p += (size_t)D * D * 2;
  u16* wkb = (u16*)p; p += (size_t)D * D * 2;
  u16* wvb = (u16*)p; p += (size_t)D * D * 2;
  u16* wob = (u16*)p; p += (size_t)D * D * 2;
  u16* Qb  = (u16*)p; p += (size_t)T * D * 2;
  u16* Kb  = (u16*)p; p += (size_t)T * D * 2;
  u16* VTb = (u16*)p; p += (size_t)D * T * 2;  // V^T [D][T]
  u16* Ab  = xb;  // xb dead after QKV gemm -> reuse for attn output

  // single convert launch: x (8192 blocks) + 4 weights (4096 blocks)
  cvt_all_kernel<<<dim3(12288), dim3(256), 0, stream>>>(x, Wq, Wk, Wv, Wo,
                                                        xb, wqb, wkb, wvb, wob);

  // 128^2 dbuf QKV: 8 xcd x 3 gemm x 8 byi x 8 bx = 1536 blocks; 3 exact rounds @ 2/CU
  gemm_qkv_kernel<<<dim3(1536), dim3(256), 0, stream>>>(xb, wqb, wkb, wvb, Qb, Kb, VTb, T, D);

  // grid: x = bh (XCD locality), y = 8 paired q-range blocks
  attn_kernel<<<dim3(B * H, 8), dim3(512), 0, stream>>>(Qb, Kb, VTb, Ab, S, H, D, T);

  gemm_out_kernel<<<dim3(512), dim3(256), 0, stream>>>(Ab, wob, out, T, D);
}

// Round 4
// 145.274 us; speedup vs baseline: 1.2545x; 1.0030x over previous
//
#include <hip/hip_runtime.h>
#include <hip/hip_bf16.h>
#include <stdint.h>

typedef unsigned short u16;
typedef __attribute__((ext_vector_type(8))) short bf16x8;
typedef __attribute__((ext_vector_type(4))) float f32x4;
typedef __attribute__((ext_vector_type(16))) float f32x16;

#define AS1 __attribute__((address_space(1)))
#define AS3 __attribute__((address_space(3)))

__device__ __forceinline__ u16 f2bf(float f) {
  union { float f; uint32_t u; } v; v.f = f;
  uint32_t u = v.u;
  return (u16)((u + 0x7FFFu + ((u >> 16) & 1u)) >> 16);
}

// packed f32x2 -> bf16x2 (RNE), single instruction
__device__ __forceinline__ uint32_t cvtpk(float lo, float hi) {
  uint32_t d;
  asm("v_cvt_pk_bf16_f32 %0, %1, %2" : "=v"(d) : "v"(lo), "v"(hi));
  return d;
}

// ---------------- fp32 -> bf16 convert (single launch for x + 4 weights) ----------------
// blocks 0..8191: x (8192*1024 elems). blocks 8192..12287: weights, 1024 blocks each.
__global__ __launch_bounds__(256) void cvt_all_kernel(const float* __restrict__ x,
    const float* __restrict__ Wq, const float* __restrict__ Wk,
    const float* __restrict__ Wv, const float* __restrict__ Wo,
    u16* __restrict__ xb, u16* __restrict__ wqb, u16* __restrict__ wkb,
    u16* __restrict__ wvb, u16* __restrict__ wob) {
  const int bid = blockIdx.x;
  const float* s;
  u16* d;
  int i;
  if (bid < 8192) {
    s = x; d = xb; i = bid * 256 + threadIdx.x;
  } else {
    const int w = (bid - 8192) >> 10;
    i = ((bid - 8192) & 1023) * 256 + threadIdx.x;
    s = (w == 0) ? Wq : (w == 1) ? Wk : (w == 2) ? Wv : Wo;
    d = (w == 0) ? wqb : (w == 1) ? wkb : (w == 2) ? wvb : wob;
  }
  float4 v = reinterpret_cast<const float4*>(s)[i];
  uint2 o;
  o.x = cvtpk(v.x, v.y);
  o.y = cvtpk(v.z, v.w);
  reinterpret_cast<uint2*>(d)[i] = o;
}

// Q pre-scaled by 1/sqrt(d_k) * log2(e) so attention uses raw exp2.
#define QSCALE 0.18033688011112042f

// ---------------- 128x128 / BK=64 double-buffered GEMM, 2 blocks/CU ----------------
#define GK 64

template <int MODE, int KC, typename OutT>
__device__ __forceinline__ void gemm128_body(u16* __restrict__ lds,
    const u16* __restrict__ A, const u16* __restrict__ Bm, OutT* __restrict__ C,
    int M, int N, int by, int bx, float oscale) {
  const int tid = threadIdx.x;            // 0..255
  const int lane = tid & 63;
  const int wave = tid >> 6;              // 0..3
  const int wm = wave >> 1, wn = wave & 1;  // 2M x 2N; wave tile 64x64
  const int l15 = lane & 15, lhi = lane >> 4;
  const int axor = (lane & 7) << 4;       // row&7 == lane&7 for all frag reads

  // staging: one gload = 256 thr x 16B = 4KB = 32 rows; thread -> (row=tid>>3, slot=(tid&7)^(row&7))
  const int srow = tid >> 3;                          // 0..31
  const int scol = (((tid & 7) ^ (srow & 7)) << 4);   // pre-swizzled source col byte
  const size_t Kb = (size_t)KC * 2;
  const uint8_t* Ag = (const uint8_t*)A + (size_t)(by * 128 + srow) * Kb + scol;
  const uint8_t* Bg = (const uint8_t*)Bm + (size_t)(bx * 128 + srow) * Kb + scol;
  uint8_t* Lb = (uint8_t*)lds;  // [buf*32768 | +16384 for B][c*4096 + tid*16]

#define STG128(bufi, kt)                                                                  \
  do {                                                                                    \
    _Pragma("unroll") for (int c = 0; c < 4; ++c) {                                       \
      __builtin_amdgcn_global_load_lds(                                                   \
          (const AS1 uint32_t*)(Ag + (size_t)c * 32 * Kb + (size_t)(kt) * 128),           \
          (AS3 uint32_t*)(Lb + (bufi) * 32768 + c * 4096 + tid * 16), 16, 0, 0);          \
      __builtin_amdgcn_global_load_lds(                                                   \
          (const AS1 uint32_t*)(Bg + (size_t)c * 32 * Kb + (size_t)(kt) * 128),           \
          (AS3 uint32_t*)(Lb + (bufi) * 32768 + 16384 + c * 4096 + tid * 16), 16, 0, 0);  \
    }                                                                                     \
  } while (0)

  const f32x4 fzero = {0.f, 0.f, 0.f, 0.f};
  f32x4 acc[4][4];
#pragma unroll
  for (int m = 0; m < 4; ++m)
#pragma unroll
    for (int n = 0; n < 4; ++n) acc[m][n] = fzero;

  constexpr int NT = KC / GK;  // 16

  STG128(0, 0);
  __syncthreads();

#pragma unroll
  for (int t = 0; t < NT; ++t) {
    const int cur = t & 1;
    if (t + 1 < NT) STG128(cur ^ 1, t + 1);  // prefetch next tile into other buffer
    const uint8_t* Ab = Lb + cur * 32768;
    const uint8_t* Bb = Ab + 16384;
    bf16x8 aF[4][2], bF[4][2];
#pragma unroll
    for (int ff = 0; ff < 4; ++ff)
#pragma unroll
      for (int ks = 0; ks < 2; ++ks) {
        aF[ff][ks] = *reinterpret_cast<const bf16x8*>(
            Ab + (wm * 64 + ff * 16 + l15) * 128 + ((ks * 64 + lhi * 16) ^ axor));
        bF[ff][ks] = *reinterpret_cast<const bf16x8*>(
            Bb + (wn * 64 + ff * 16 + l15) * 128 + ((ks * 64 + lhi * 16) ^ axor));
      }
    __builtin_amdgcn_s_setprio(1);
#pragma unroll
    for (int mm = 0; mm < 4; ++mm)
#pragma unroll
      for (int nn = 0; nn < 4; ++nn)
#pragma unroll
        for (int ks = 0; ks < 2; ++ks)
          acc[mm][nn] = __builtin_amdgcn_mfma_f32_16x16x32_bf16(aF[mm][ks], bF[nn][ks],
                                                                acc[mm][nn], 0, 0, 0);
    __builtin_amdgcn_s_setprio(0);
    __syncthreads();  // drains this step's gloads (vmcnt 0) + orders buffer reuse
  }

  // ---- epilogue ----
#pragma unroll
  for (int mf = 0; mf < 4; ++mf)
#pragma unroll
    for (int nf = 0; nf < 4; ++nf) {
      const int row0 = by * 128 + wm * 64 + mf * 16 + lhi * 4;
      const int col = bx * 128 + wn * 64 + nf * 16 + l15;
      if constexpr (MODE == 2) {
        uint2 pk;
        pk.x = cvtpk(acc[mf][nf][0], acc[mf][nf][1]);
        pk.y = cvtpk(acc[mf][nf][2], acc[mf][nf][3]);
        *reinterpret_cast<uint2*>((u16*)C + (size_t)col * M + row0) = pk;
      } else if constexpr (MODE == 1) {
#pragma unroll
        for (int r = 0; r < 4; ++r)
          ((float*)C)[(size_t)(row0 + r) * N + col] = acc[mf][nf][r];
      } else {
#pragma unroll
        for (int r = 0; r < 4; ++r)
          ((u16*)C)[(size_t)(row0 + r) * N + col] = f2bf(acc[mf][nf][r] * oscale);
      }
    }
#undef STG128
}

// Grid 1536 = 8 xcd x 3 bz x 8 byi x 8 bx; 3 exact rounds at 2 blocks/CU.
__global__ __launch_bounds__(256, 2) void gemm_qkv_kernel(const u16* __restrict__ A,
    const u16* __restrict__ W0, const u16* __restrict__ W1, const u16* __restrict__ W2,
    u16* __restrict__ OQ, u16* __restrict__ OK, u16* __restrict__ OVT, int M, int N) {
  __shared__ u16 lds[2][2][128 * GK];  // 64 KB
  const int id = blockIdx.x;           // 0..1535
  const int xcd = id & 7;
  const int slot = id >> 3;            // 0..191
  const int bz = slot >> 6;            // 0..2
  const int r = slot & 63;
  const int byi = r >> 3, bx = r & 7;
  const int by = xcd + 8 * byi;        // 0..63
  if (bz == 0)      gemm128_body<0, 1024, u16>(&lds[0][0][0], A, W0, OQ,  M, N, by, bx, QSCALE);
  else if (bz == 1) gemm128_body<0, 1024, u16>(&lds[0][0][0], A, W1, OK,  M, N, by, bx, 1.f);
  else              gemm128_body<2, 1024, u16>(&lds[0][0][0], A, W2, OVT, M, N, by, bx, 1.f);
}

// 512 blocks = 1 exact round at 2 blocks/CU.
__global__ __launch_bounds__(256, 2) void gemm_out_kernel(const u16* __restrict__ A,
    const u16* __restrict__ Bm, float* __restrict__ C, int M, int N) {
  __shared__ u16 lds[2][2][128 * GK];  // 64 KB
  const int id = blockIdx.x;           // 0..511
  const int xcd = id & 7;
  const int slot = id >> 3;            // 0..63
  const int byi = slot >> 3, bx = slot & 7;
  const int by = xcd + 8 * byi;
  gemm128_body<1, 1024, float>(&lds[0][0][0], A, Bm, C, M, N, by, bx, 1.f);
}

// ---------------- causal flash attention v7: per-wave hi+lo q pairing ----------------
// 4 waves x (one 32-row HIGH q block + its mirror 32-row LOW q block). Every wave's
// total tile count ~= (hi_tiles + lo_tiles) ~= S/KVB -> no idle waves (v6 had waves
// 4-7 idle ~70% of the loop; MfmaUtil 19%). Grid 64bh x 8 = 512 blocks of 256 thr,
// launch_bounds(256,2) -> all blocks co-resident (2/CU), equal per-block work.
#define KVB 64

__device__ __forceinline__ void attn_tile(const u16* __restrict__ KB,
    const u16* __restrict__ VB, const bf16x8 (&qf)[4], f32x16 (&acc)[2],
    float& mrow, float& lrow, int kv, int qv, int qr, int l31, int lh) {
  // ---- QK^T: sc[bb] covers kv rows bb*32..bb*32+31, q = l31 ----
  f32x16 sc[2];
#pragma unroll
  for (int bb = 0; bb < 2; ++bb) {
#pragma unroll
    for (int r = 0; r < 16; ++r) sc[bb][r] = 0.f;
#pragma unroll
    for (int dc = 0; dc < 4; ++dc) {
      const bf16x8 kf = *reinterpret_cast<const bf16x8*>(
          KB + (bb * 32 + l31) * 64 + (((dc * 2 + lh) ^ (l31 & 7)) << 3));
      sc[bb] = __builtin_amdgcn_mfma_f32_32x32x16_bf16(kf, qf[dc], sc[bb], 0, 0, 0);
    }
  }

  // ---- causal mask + row max (in-reg fmax + 1 shfl) ----
  const bool msk = (kv + KVB - 1 > qv);
  float bmax = -3e38f;
#pragma unroll
  for (int bb = 0; bb < 2; ++bb)
#pragma unroll
    for (int r = 0; r < 16; ++r) {
      float v = sc[bb][r];
      if (msk) {
        const int kvg = kv + bb * 32 + (r & 3) + 8 * (r >> 2) + 4 * lh;
        v = (kvg > qr) ? -1e30f : v;
        sc[bb][r] = v;
      }
      bmax = fmaxf(bmax, v);
    }
  bmax = fmaxf(bmax, __shfl_xor(bmax, 32, 64));

  // ---- defer-max rescale ----
  if (!__all(bmax <= mrow + 6.f)) {
    const float mn = fmaxf(mrow, bmax);
    const float fac = __builtin_amdgcn_exp2f(mrow - mn);
    mrow = mn;
    lrow *= fac;
#pragma unroll
    for (int db = 0; db < 2; ++db)
#pragma unroll
      for (int r = 0; r < 16; ++r) acc[db][r] *= fac;
  }

  // ---- exp2 + per-lane partial sum ----
  float rs = 0.f;
#pragma unroll
  for (int bb = 0; bb < 2; ++bb)
#pragma unroll
    for (int r = 0; r < 16; ++r) {
      const float p = __builtin_amdgcn_exp2f(sc[bb][r] - mrow);
      sc[bb][r] = p;
      rs += p;
    }
  lrow += rs;

  // ---- PV: per 16-kv chunk, build P B-frag in regs via cvt_pk + permlane32_swap ----
#pragma unroll
  for (int cc = 0; cc < 4; ++cc) {
    const int bb = cc >> 1, c2 = cc & 1;
    uint32_t a0 = cvtpk(sc[bb][8 * c2 + 0], sc[bb][8 * c2 + 1]);
    uint32_t a1 = cvtpk(sc[bb][8 * c2 + 2], sc[bb][8 * c2 + 3]);
    uint32_t b0 = cvtpk(sc[bb][8 * c2 + 4], sc[bb][8 * c2 + 5]);
    uint32_t b1 = cvtpk(sc[bb][8 * c2 + 6], sc[bb][8 * c2 + 7]);
    asm("v_permlane32_swap_b32 %0, %1" : "+v"(a0), "+v"(b0));
    asm("v_permlane32_swap_b32 %0, %1" : "+v"(a1), "+v"(b1));
    union { uint32_t u[4]; bf16x8 v8; } pf;
    pf.u[0] = a0; pf.u[1] = a1; pf.u[2] = b0; pf.u[3] = b1;
#pragma unroll
    for (int db = 0; db < 2; ++db) {
      const bf16x8 vfg = *reinterpret_cast<const bf16x8*>(
          VB + (db * 32 + l31) * 64 + (((cc * 2 + lh) ^ (l31 & 7)) << 3));
      acc[db] = __builtin_amdgcn_mfma_f32_32x32x16_bf16(vfg, pf.v8, acc[db], 0, 0, 0);
    }
  }
}

__global__ __launch_bounds__(256, 2) void attn_kernel(const u16* __restrict__ Q,
    const u16* __restrict__ Kg, const u16* __restrict__ VTg, u16* __restrict__ O,
    int S, int H, int Dm, int T) {
  const int bh = blockIdx.x;
  const int b = bh / H, h = bh % H;
  const int y = blockIdx.y;           // 0..7
  const int qh0 = 1920 - 128 * y;     // high strip base (covers [1024,2048) over y)
  const int ql0 = 128 * y;            // mirror low strip base (covers [0,1024))
  const int tid = threadIdx.x;        // 0..255
  const int lane = tid & 63, wave = tid >> 6;  // 4 waves
  const int l31 = lane & 31, lh = lane >> 5;

  __shared__ u16 KVs[2][2][64 * 64];  // [buf][K=0/V=1], col-block swizzle ^((row&7)<<3)  (32KB)

  const u16* Qh = Q + ((size_t)b * S) * Dm + h * 64;
  const u16* Kh = Kg + ((size_t)b * S) * Dm + h * 64;
  const u16* Vh = VTg + (size_t)(h * 64) * T + (size_t)b * S;
  const int qvH = qh0 + wave * 32, qvL = ql0 + wave * 32;
  const int qrH = qvH + l31, qrL = qvL + l31;

  // Q frags (B-operand 32x32x16): col = q = l31, k = dc*16 + lh*8 + j
  bf16x8 qfH[4], qfL[4];
#pragma unroll
  for (int dc = 0; dc < 4; ++dc) {
    qfH[dc] = *reinterpret_cast<const bf16x8*>(Qh + (size_t)qrH * Dm + dc * 16 + lh * 8);
    qfL[dc] = *reinterpret_cast<const bf16x8*>(Qh + (size_t)qrL * Dm + dc * 16 + lh * 8);
  }

  f32x16 accH[2], accL[2];  // O^T: d = db*32 + (reg&3)+8*(reg>>2)+4*lh, q = l31
#pragma unroll
  for (int db = 0; db < 2; ++db)
#pragma unroll
    for (int r = 0; r < 16; ++r) { accH[db][r] = 0.f; accL[db][r] = 0.f; }
  float mH = -1e30f, lH = 0.f, mL = -1e30f, lL = 0.f;

  // staging: 256 thr, 4 gloads (K rows 0-31, 32-63; V d-rows 0-31, 32-63), 16B each.
#define STAGE(bufi, kvoff)                                                                     \
  do {                                                                                         \
    const int sr = tid >> 3;                                                                   \
    const int sc_ = (((tid & 7) ^ (sr & 7)) << 3);                                             \
    _Pragma("unroll") for (int j = 0; j < 2; ++j) {                                            \
      __builtin_amdgcn_global_load_lds(                                                        \
          (const AS1 uint32_t*)(Kh + (size_t)((kvoff) + j * 32 + sr) * Dm + sc_),              \
          (AS3 uint32_t*)(&KVs[bufi][0][j * 2048 + tid * 8]), 16, 0, 0);                       \
      __builtin_amdgcn_global_load_lds(                                                        \
          (const AS1 uint32_t*)(Vh + (size_t)(j * 32 + sr) * T + (kvoff) + sc_),               \
          (AS3 uint32_t*)(&KVs[bufi][1][j * 2048 + tid * 8]), 16, 0, 0);                       \
    }                                                                                          \
  } while (0)

  const int nt = (qh0 + 128) / 64;  // 32 - 2y tiles
  STAGE(0, 0);
  int buf = 0;

  for (int t = 0; t < nt; ++t) {
    __syncthreads();
    const int kv = t * KVB;
    if (t + 1 < nt) STAGE(buf ^ 1, (t + 1) * KVB);
    const u16* KB = KVs[buf][0];
    const u16* VB = KVs[buf][1];
    if (kv <= qvH + 31) attn_tile(KB, VB, qfH, accH, mH, lH, kv, qvH, qrH, l31, lh);
    if (kv <= qvL + 31) attn_tile(KB, VB, qfL, accL, mL, lL, kv, qvL, qrL, l31, lh);
    buf ^= 1;
  }

  // ---- epilogue: finish l, O^T regs -> LDS (row-swizzled) -> coalesced 16B stores ----
  lH += __shfl_xor(lH, 32, 64);
  lL += __shfl_xor(lL, 32, 64);
  const float invH = 1.f / lH, invL = 1.f / lL;
  __syncthreads();
  u16* Ost = &KVs[0][0][0];  // 32 KB = [256 rows][64 d]; rows 0-127 = hi strip, 128-255 = lo
  {
#pragma unroll
    for (int s = 0; s < 2; ++s) {
      const int row = s * 128 + wave * 32 + l31;
      const f32x16* ac = s ? accL : accH;
      const float inv = s ? invL : invH;
#pragma unroll
      for (int db = 0; db < 2; ++db)
#pragma unroll
        for (int g = 0; g < 4; ++g) {
          uint2 pk;
          pk.x = cvtpk(ac[db][4 * g + 0] * inv, ac[db][4 * g + 1] * inv);
          pk.y = cvtpk(ac[db][4 * g + 2] * inv, ac[db][4 * g + 3] * inv);
          const int blk = 4 * db + g;  // d = db*32 + 8g + 4lh + 0..3
          const int addr = row * 64 + (((blk ^ (row & 7)) << 3)) + 4 * lh;
          *reinterpret_cast<uint2*>(Ost + addr) = pk;
        }
    }
  }
  __syncthreads();
#pragma unroll
  for (int p = 0; p < 8; ++p) {
    const int idx = p * 256 + tid;
    const int row = idx >> 3, seg = idx & 7;
    const float4 v = *reinterpret_cast<const float4*>(Ost + row * 64 + ((seg ^ (row & 7)) << 3));
    const int q = (row < 128) ? (qh0 + row) : (ql0 + row - 128);
    *reinterpret_cast<float4*>(O + ((size_t)b * S + q) * Dm + h * 64 + seg * 8) = v;
  }
#undef STAGE
}

// ---------------- launch ----------------
extern "C" void kernel_launch(void* const* d_in, const int* in_sizes, int n_in,
                              void* d_out, int out_size, void* d_ws, size_t ws_size,
                              hipStream_t stream) {
  const float* x  = (const float*)d_in[0];
  const float* Wq = (const float*)d_in[1];
  const float* Wk = (const float*)d_in[2];
  const float* Wv = (const float*)d_in[3];
  const float* Wo = (const float*)d_in[4];
  float* out = (float*)d_out;

  const int B = 4, S = 2048, D = 1024, H = 16;
  const int T = B * S;  // 8192

  uint8_t* p = (uint8_t*)d_ws;
  u16* xb  = (u16*)p; p += (size_t)T * D * 2;
  u16* wqb = (u16*)p; p += (size_t)D * D * 2;
  u16* wkb = (u16*)p; p += (size_t)D * D * 2;
  u16* wvb = (u16*)p; p += (size_t)D * D * 2;
  u16* wob = (u16*)p; p += (size_t)D * D * 2;
  u16* Qb  = (u16*)p; p += (size_t)T * D * 2;
  u16* Kb  = (u16*)p; p += (size_t)T * D * 2;
  u16* VTb = (u16*)p; p += (size_t)D * T * 2;  // V^T [D][T]
  u16* Ab  = xb;  // xb dead after QKV gemm -> reuse for attn output

  // single convert launch: x (8192 blocks) + 4 weights (4096 blocks)
  cvt_all_kernel<<<dim3(12288), dim3(256), 0, stream>>>(x, Wq, Wk, Wv, Wo,
                                                        xb, wqb, wkb, wvb, wob);

  // 128^2 dbuf QKV: 8 xcd x 3 gemm x 8 byi x 8 bx = 1536 blocks; 3 exact rounds @ 2/CU
  gemm_qkv_kernel<<<dim3(1536), dim3(256), 0, stream>>>(xb, wqb, wkb, wvb, Qb, Kb, VTb, T, D);

  // attn v7: 64 bh x 8 strips, 256-thr blocks, all co-resident
  attn_kernel<<<dim3(B * H, 8), dim3(256), 0, stream>>>(Qb, Kb, VTb, Ab, S, H, D, T);

  gemm_out_kernel<<<dim3(512), dim3(256), 0, stream>>>(Ab, wob, out, T, D);
}

// Round 5
// 136.703 us; speedup vs baseline: 1.3332x; 1.0627x over previous
//
#include <hip/hip_runtime.h>
#include <hip/hip_bf16.h>
#include <stdint.h>

typedef unsigned short u16;
typedef __attribute__((ext_vector_type(8))) short bf16x8;
typedef __attribute__((ext_vector_type(4))) float f32x4;
typedef __attribute__((ext_vector_type(16))) float f32x16;

#define AS1 __attribute__((address_space(1)))
#define AS3 __attribute__((address_space(3)))

__device__ __forceinline__ u16 f2bf(float f) {
  union { float f; uint32_t u; } v; v.f = f;
  uint32_t u = v.u;
  return (u16)((u + 0x7FFFu + ((u >> 16) & 1u)) >> 16);
}

// packed f32x2 -> bf16x2 (RNE), single instruction
__device__ __forceinline__ uint32_t cvtpk(float lo, float hi) {
  uint32_t d;
  asm("v_cvt_pk_bf16_f32 %0, %1, %2" : "=v"(d) : "v"(lo), "v"(hi));
  return d;
}

// ---------------- fp32 -> bf16 convert (single launch for x + 4 weights) ----------------
// blocks 0..8191: x (8192*1024 elems). blocks 8192..12287: weights, 1024 blocks each.
__global__ __launch_bounds__(256) void cvt_all_kernel(const float* __restrict__ x,
    const float* __restrict__ Wq, const float* __restrict__ Wk,
    const float* __restrict__ Wv, const float* __restrict__ Wo,
    u16* __restrict__ xb, u16* __restrict__ wqb, u16* __restrict__ wkb,
    u16* __restrict__ wvb, u16* __restrict__ wob) {
  const int bid = blockIdx.x;
  const float* s;
  u16* d;
  int i;
  if (bid < 8192) {
    s = x; d = xb; i = bid * 256 + threadIdx.x;
  } else {
    const int w = (bid - 8192) >> 10;
    i = ((bid - 8192) & 1023) * 256 + threadIdx.x;
    s = (w == 0) ? Wq : (w == 1) ? Wk : (w == 2) ? Wv : Wo;
    d = (w == 0) ? wqb : (w == 1) ? wkb : (w == 2) ? wvb : wob;
  }
  float4 v = reinterpret_cast<const float4*>(s)[i];
  uint2 o;
  o.x = cvtpk(v.x, v.y);
  o.y = cvtpk(v.z, v.w);
  reinterpret_cast<uint2*>(d)[i] = o;
}

// Q pre-scaled by 1/sqrt(d_k) * log2(e) so attention uses raw exp2.
#define QSCALE 0.18033688011112042f

// ---------------- 128x128 / BK=64 double-buffered GEMM, 2 blocks/CU ----------------
#define GK 64

template <int MODE, int KC, typename OutT>
__device__ __forceinline__ void gemm128_body(u16* __restrict__ lds,
    const u16* __restrict__ A, const u16* __restrict__ Bm, OutT* __restrict__ C,
    int M, int N, int by, int bx, float oscale) {
  const int tid = threadIdx.x;            // 0..255
  const int lane = tid & 63;
  const int wave = tid >> 6;              // 0..3
  const int wm = wave >> 1, wn = wave & 1;  // 2M x 2N; wave tile 64x64
  const int l15 = lane & 15, lhi = lane >> 4;
  const int axor = (lane & 7) << 4;       // row&7 == lane&7 for all frag reads

  // staging: one gload = 256 thr x 16B = 4KB = 32 rows; thread -> (row=tid>>3, slot=(tid&7)^(row&7))
  const int srow = tid >> 3;                          // 0..31
  const int scol = (((tid & 7) ^ (srow & 7)) << 4);   // pre-swizzled source col byte
  const size_t Kb = (size_t)KC * 2;
  const uint8_t* Ag = (const uint8_t*)A + (size_t)(by * 128 + srow) * Kb + scol;
  const uint8_t* Bg = (const uint8_t*)Bm + (size_t)(bx * 128 + srow) * Kb + scol;
  uint8_t* Lb = (uint8_t*)lds;  // [buf*32768 | +16384 for B][c*4096 + tid*16]

#define STG128(bufi, kt)                                                                  \
  do {                                                                                    \
    _Pragma("unroll") for (int c = 0; c < 4; ++c) {                                       \
      __builtin_amdgcn_global_load_lds(                                                   \
          (const AS1 uint32_t*)(Ag + (size_t)c * 32 * Kb + (size_t)(kt) * 128),           \
          (AS3 uint32_t*)(Lb + (bufi) * 32768 + c * 4096 + tid * 16), 16, 0, 0);          \
      __builtin_amdgcn_global_load_lds(                                                   \
          (const AS1 uint32_t*)(Bg + (size_t)c * 32 * Kb + (size_t)(kt) * 128),           \
          (AS3 uint32_t*)(Lb + (bufi) * 32768 + 16384 + c * 4096 + tid * 16), 16, 0, 0);  \
    }                                                                                     \
  } while (0)

  const f32x4 fzero = {0.f, 0.f, 0.f, 0.f};
  f32x4 acc[4][4];
#pragma unroll
  for (int m = 0; m < 4; ++m)
#pragma unroll
    for (int n = 0; n < 4; ++n) acc[m][n] = fzero;

  constexpr int NT = KC / GK;  // 16

  STG128(0, 0);
  __syncthreads();

#pragma unroll
  for (int t = 0; t < NT; ++t) {
    const int cur = t & 1;
    if (t + 1 < NT) STG128(cur ^ 1, t + 1);  // prefetch next tile into other buffer
    const uint8_t* Ab = Lb + cur * 32768;
    const uint8_t* Bb = Ab + 16384;
    bf16x8 aF[4][2], bF[4][2];
#pragma unroll
    for (int ff = 0; ff < 4; ++ff)
#pragma unroll
      for (int ks = 0; ks < 2; ++ks) {
        aF[ff][ks] = *reinterpret_cast<const bf16x8*>(
            Ab + (wm * 64 + ff * 16 + l15) * 128 + ((ks * 64 + lhi * 16) ^ axor));
        bF[ff][ks] = *reinterpret_cast<const bf16x8*>(
            Bb + (wn * 64 + ff * 16 + l15) * 128 + ((ks * 64 + lhi * 16) ^ axor));
      }
    __builtin_amdgcn_s_setprio(1);
#pragma unroll
    for (int mm = 0; mm < 4; ++mm)
#pragma unroll
      for (int nn = 0; nn < 4; ++nn)
#pragma unroll
        for (int ks = 0; ks < 2; ++ks)
          acc[mm][nn] = __builtin_amdgcn_mfma_f32_16x16x32_bf16(aF[mm][ks], bF[nn][ks],
                                                                acc[mm][nn], 0, 0, 0);
    __builtin_amdgcn_s_setprio(0);
    __syncthreads();  // drains this step's gloads (vmcnt 0) + orders buffer reuse
  }

  // ---- epilogue ----
#pragma unroll
  for (int mf = 0; mf < 4; ++mf)
#pragma unroll
    for (int nf = 0; nf < 4; ++nf) {
      const int row0 = by * 128 + wm * 64 + mf * 16 + lhi * 4;
      const int col = bx * 128 + wn * 64 + nf * 16 + l15;
      if constexpr (MODE == 2) {
        uint2 pk;
        pk.x = cvtpk(acc[mf][nf][0], acc[mf][nf][1]);
        pk.y = cvtpk(acc[mf][nf][2], acc[mf][nf][3]);
        *reinterpret_cast<uint2*>((u16*)C + (size_t)col * M + row0) = pk;
      } else if constexpr (MODE == 1) {
#pragma unroll
        for (int r = 0; r < 4; ++r)
          ((float*)C)[(size_t)(row0 + r) * N + col] = acc[mf][nf][r];
      } else {
#pragma unroll
        for (int r = 0; r < 4; ++r)
          ((u16*)C)[(size_t)(row0 + r) * N + col] = f2bf(acc[mf][nf][r] * oscale);
      }
    }
#undef STG128
}

// Grid 1536 = 8 xcd x 3 bz x 8 byi x 8 bx; 3 exact rounds at 2 blocks/CU.
__global__ __launch_bounds__(256, 2) void gemm_qkv_kernel(const u16* __restrict__ A,
    const u16* __restrict__ W0, const u16* __restrict__ W1, const u16* __restrict__ W2,
    u16* __restrict__ OQ, u16* __restrict__ OK, u16* __restrict__ OVT, int M, int N) {
  __shared__ u16 lds[2][2][128 * GK];  // 64 KB
  const int id = blockIdx.x;           // 0..1535
  const int xcd = id & 7;
  const int slot = id >> 3;            // 0..191
  const int bz = slot >> 6;            // 0..2
  const int r = slot & 63;
  const int byi = r >> 3, bx = r & 7;
  const int by = xcd + 8 * byi;        // 0..63
  if (bz == 0)      gemm128_body<0, 1024, u16>(&lds[0][0][0], A, W0, OQ,  M, N, by, bx, QSCALE);
  else if (bz == 1) gemm128_body<0, 1024, u16>(&lds[0][0][0], A, W1, OK,  M, N, by, bx, 1.f);
  else              gemm128_body<2, 1024, u16>(&lds[0][0][0], A, W2, OVT, M, N, by, bx, 1.f);
}

// 512 blocks = 1 exact round at 2 blocks/CU.
__global__ __launch_bounds__(256, 2) void gemm_out_kernel(const u16* __restrict__ A,
    const u16* __restrict__ Bm, float* __restrict__ C, int M, int N) {
  __shared__ u16 lds[2][2][128 * GK];  // 64 KB
  const int id = blockIdx.x;           // 0..511
  const int xcd = id & 7;
  const int slot = id >> 3;            // 0..63
  const int byi = slot >> 3, bx = slot & 7;
  const int by = xcd + 8 * byi;
  gemm128_body<1, 1024, float>(&lds[0][0][0], A, Bm, C, M, N, by, bx, 1.f);
}

// ---------------- causal flash attention v8: KVB=128, per-32kv sub-blocks ----------------
// 4 waves x (32-row HIGH q block + mirror 32-row LOW q block). KV staged 128 rows/iter
// (half the iterations, quarter the barriers of v6/v7). Each 32-kv sub-block is a
// self-contained mini-softmax: QK(4 MFMA) -> depth-4 tree max -> defer rescale ->
// exp2 -> tree sum -> PV(4 MFMA). Fully-masked sub-blocks are skipped (uniform branch).
#define KVB 128

__device__ __forceinline__ void attn_bb(const u16* __restrict__ KB,
    const u16* __restrict__ VB, const bf16x8 (&qf)[4], f32x16 (&acc)[2],
    float& mrow, float& lrow, int kvb, int qr, bool boundary, int bb, int l31, int lh) {
  // ---- QK^T for kv rows kvb..kvb+31 (LDS K rows bb*32..), q = l31 ----
  f32x16 sc;
#pragma unroll
  for (int r = 0; r < 16; ++r) sc[r] = 0.f;
#pragma unroll
  for (int dc = 0; dc < 4; ++dc) {
    const bf16x8 kf = *reinterpret_cast<const bf16x8*>(
        KB + (bb * 32 + l31) * 64 + (((dc * 2 + lh) ^ (l31 & 7)) << 3));
    sc = __builtin_amdgcn_mfma_f32_32x32x16_bf16(kf, qf[dc], sc, 0, 0, 0);
  }
  // ---- causal mask (boundary sub-block only; uniform branch) ----
  if (boundary) {
#pragma unroll
    for (int r = 0; r < 16; ++r) {
      const int kvg = kvb + (r & 3) + 8 * (r >> 2) + 4 * lh;
      sc[r] = (kvg > qr) ? -1e30f : sc[r];
    }
  }
  // ---- depth-4 tree max + cross-half shfl ----
  float t0 = fmaxf(sc[0], sc[8]),  t1 = fmaxf(sc[1], sc[9]);
  float t2 = fmaxf(sc[2], sc[10]), t3 = fmaxf(sc[3], sc[11]);
  float t4 = fmaxf(sc[4], sc[12]), t5 = fmaxf(sc[5], sc[13]);
  float t6 = fmaxf(sc[6], sc[14]), t7 = fmaxf(sc[7], sc[15]);
  t0 = fmaxf(t0, t4); t1 = fmaxf(t1, t5); t2 = fmaxf(t2, t6); t3 = fmaxf(t3, t7);
  float bmax = fmaxf(fmaxf(t0, t1), fmaxf(t2, t3));
  bmax = fmaxf(bmax, __shfl_xor(bmax, 32, 64));
  // ---- defer-max rescale (vector-form acc scale) ----
  if (!__all(bmax <= mrow + 6.f)) {
    const float mn = fmaxf(mrow, bmax);
    const float fac = __builtin_amdgcn_exp2f(mrow - mn);
    mrow = mn;
    lrow *= fac;
    acc[0] *= fac;
    acc[1] *= fac;
  }
  // ---- exp2 + depth-4 tree sum ----
#pragma unroll
  for (int r = 0; r < 16; ++r) sc[r] = __builtin_amdgcn_exp2f(sc[r] - mrow);
  float s0 = sc[0] + sc[8],  s1 = sc[1] + sc[9];
  float s2 = sc[2] + sc[10], s3 = sc[3] + sc[11];
  float s4 = sc[4] + sc[12], s5 = sc[5] + sc[13];
  float s6 = sc[6] + sc[14], s7 = sc[7] + sc[15];
  s0 += s4; s1 += s5; s2 += s6; s3 += s7;
  lrow += (s0 + s1) + (s2 + s3);
  // ---- PV: two 16-kv chunks; P B-frag via cvt_pk + permlane32_swap ----
#pragma unroll
  for (int cc = 0; cc < 2; ++cc) {
    uint32_t a0 = cvtpk(sc[8 * cc + 0], sc[8 * cc + 1]);
    uint32_t a1 = cvtpk(sc[8 * cc + 2], sc[8 * cc + 3]);
    uint32_t b0 = cvtpk(sc[8 * cc + 4], sc[8 * cc + 5]);
    uint32_t b1 = cvtpk(sc[8 * cc + 6], sc[8 * cc + 7]);
    asm("v_permlane32_swap_b32 %0, %1" : "+v"(a0), "+v"(b0));
    asm("v_permlane32_swap_b32 %0, %1" : "+v"(a1), "+v"(b1));
    union { uint32_t u[4]; bf16x8 v8; } pf;
    pf.u[0] = a0; pf.u[1] = a1; pf.u[2] = b0; pf.u[3] = b1;
    const int c2 = bb * 2 + cc;  // global 16-kv chunk 0..7
#pragma unroll
    for (int db = 0; db < 2; ++db) {
      const int blkv = ((c2 * 2 + lh) & 8) | (((c2 * 2 + lh) ^ (l31 & 7)) & 7);
      const bf16x8 vfg = *reinterpret_cast<const bf16x8*>(
          VB + (db * 32 + l31) * 128 + blkv * 8);
      acc[db] = __builtin_amdgcn_mfma_f32_32x32x16_bf16(vfg, pf.v8, acc[db], 0, 0, 0);
    }
  }
}

__global__ __launch_bounds__(256, 2) void attn_kernel(const u16* __restrict__ Q,
    const u16* __restrict__ Kg, const u16* __restrict__ VTg, u16* __restrict__ O,
    int S, int H, int Dm, int T) {
  const int bh = blockIdx.x;
  const int b = bh / H, h = bh % H;
  const int y = blockIdx.y;           // 0..7
  const int qh0 = 1920 - 128 * y;     // high strip base (covers [1024,2048) over y)
  const int ql0 = 128 * y;            // mirror low strip base (covers [0,1024))
  const int tid = threadIdx.x;        // 0..255
  const int lane = tid & 63, wave = tid >> 6;  // 4 waves
  const int l31 = lane & 31, lh = lane >> 5;

  // [buf][K=0/V=1][8192 u16]: K = [128 kv][64 d] swz ^((row&7)<<3) on 8-u16 slots;
  // V = [64 d][128 kv] swz on low 3 bits of the 4-bit slot index.  64 KB total.
  __shared__ u16 KVs[2][2][8192];

  const u16* Qh = Q + ((size_t)b * S) * Dm + h * 64;
  const u16* Kh = Kg + ((size_t)b * S) * Dm + h * 64;
  const u16* Vh = VTg + (size_t)(h * 64) * T + (size_t)b * S;
  const int qvH = qh0 + wave * 32, qvL = ql0 + wave * 32;
  const int qrH = qvH + l31, qrL = qvL + l31;

  // Q frags (B-operand 32x32x16): col = q = l31, k = dc*16 + lh*8 + j
  bf16x8 qfH[4], qfL[4];
#pragma unroll
  for (int dc = 0; dc < 4; ++dc) {
    qfH[dc] = *reinterpret_cast<const bf16x8*>(Qh + (size_t)qrH * Dm + dc * 16 + lh * 8);
    qfL[dc] = *reinterpret_cast<const bf16x8*>(Qh + (size_t)qrL * Dm + dc * 16 + lh * 8);
  }

  f32x16 accH[2], accL[2];  // O^T: d = db*32 + (reg&3)+8*(reg>>2)+4*lh, q = l31
#pragma unroll
  for (int db = 0; db < 2; ++db)
#pragma unroll
    for (int r = 0; r < 16; ++r) { accH[db][r] = 0.f; accL[db][r] = 0.f; }
  float mH = -1e30f, lH = 0.f, mL = -1e30f, lL = 0.f;

  // staging (KVB=128): K = 4 gloads of 32 rows; V = 4 gloads of 16 d-rows.
#define STAGE(bufi, kvoff)                                                                     \
  do {                                                                                         \
    const int rK = tid >> 3;                                                                   \
    const int cK = (((tid & 7) ^ (rK & 7)) << 3);                                              \
    const int rV = tid >> 4;                                                                   \
    const int sV = tid & 15;                                                                   \
    const int cV = (((sV & 8) | ((sV ^ (rV & 7)) & 7)) << 3);                                  \
    _Pragma("unroll") for (int j = 0; j < 4; ++j) {                                            \
      __builtin_amdgcn_global_load_lds(                                                        \
          (const AS1 uint32_t*)(Kh + (size_t)((kvoff) + j * 32 + rK) * Dm + cK),               \
          (AS3 uint32_t*)(&KVs[bufi][0][j * 2048 + tid * 8]), 16, 0, 0);                       \
      __builtin_amdgcn_global_load_lds(                                                        \
          (const AS1 uint32_t*)(Vh + (size_t)(j * 16 + rV) * T + (kvoff) + cV),                \
          (AS3 uint32_t*)(&KVs[bufi][1][j * 2048 + tid * 8]), 16, 0, 0);                       \
    }                                                                                          \
  } while (0)

  const int nt = 16 - y;  // (qh0 + 128) / 128
  STAGE(0, 0);
  int buf = 0;

  for (int t = 0; t < nt; ++t) {
    __syncthreads();
    const int kv = t * KVB;
    if (t + 1 < nt) STAGE(buf ^ 1, (t + 1) * KVB);
    const u16* KB = KVs[buf][0];
    const u16* VB = KVs[buf][1];
#pragma unroll
    for (int bb = 0; bb < 4; ++bb) {
      const int kvb = kv + bb * 32;
      if (kvb <= qvH + 31)
        attn_bb(KB, VB, qfH, accH, mH, lH, kvb, qrH, (kvb + 31 > qvH), bb, l31, lh);
    }
#pragma unroll
    for (int bb = 0; bb < 4; ++bb) {
      const int kvb = kv + bb * 32;
      if (kvb <= qvL + 31)
        attn_bb(KB, VB, qfL, accL, mL, lL, kvb, qrL, (kvb + 31 > qvL), bb, l31, lh);
    }
    buf ^= 1;
  }

  // ---- epilogue: finish l, O^T regs -> LDS (row-swizzled) -> coalesced 16B stores ----
  lH += __shfl_xor(lH, 32, 64);
  lL += __shfl_xor(lL, 32, 64);
  const float invH = 1.f / lH, invL = 1.f / lL;
  __syncthreads();
  u16* Ost = &KVs[0][0][0];  // 32 KB = [256 rows][64 d]; rows 0-127 = hi strip, 128-255 = lo
  {
#pragma unroll
    for (int s = 0; s < 2; ++s) {
      const int row = s * 128 + wave * 32 + l31;
      const f32x16* ac = s ? accL : accH;
      const float inv = s ? invL : invH;
#pragma unroll
      for (int db = 0; db < 2; ++db)
#pragma unroll
        for (int g = 0; g < 4; ++g) {
          uint2 pk;
          pk.x = cvtpk(ac[db][4 * g + 0] * inv, ac[db][4 * g + 1] * inv);
          pk.y = cvtpk(ac[db][4 * g + 2] * inv, ac[db][4 * g + 3] * inv);
          const int blk = 4 * db + g;  // d = db*32 + 8g + 4lh + 0..3
          const int addr = row * 64 + (((blk ^ (row & 7)) << 3)) + 4 * lh;
          *reinterpret_cast<uint2*>(Ost + addr) = pk;
        }
    }
  }
  __syncthreads();
#pragma unroll
  for (int p = 0; p < 8; ++p) {
    const int idx = p * 256 + tid;
    const int row = idx >> 3, seg = idx & 7;
    const float4 v = *reinterpret_cast<const float4*>(Ost + row * 64 + ((seg ^ (row & 7)) << 3));
    const int q = (row < 128) ? (qh0 + row) : (ql0 + row - 128);
    *reinterpret_cast<float4*>(O + ((size_t)b * S + q) * Dm + h * 64 + seg * 8) = v;
  }
#undef STAGE
}

// ---------------- launch ----------------
extern "C" void kernel_launch(void* const* d_in, const int* in_sizes, int n_in,
                              void* d_out, int out_size, void* d_ws, size_t ws_size,
                              hipStream_t stream) {
  const float* x  = (const float*)d_in[0];
  const float* Wq = (const float*)d_in[1];
  const float* Wk = (const float*)d_in[2];
  const float* Wv = (const float*)d_in[3];
  const float* Wo = (const float*)d_in[4];
  float* out = (float*)d_out;

  const int B = 4, S = 2048, D = 1024, H = 16;
  const int T = B * S;  // 8192

  uint8_t* p = (uint8_t*)d_ws;
  u16* xb  = (u16*)p; p += (size_t)T * D * 2;
  u16* wqb = (u16*)p; p += (size_t)D * D * 2;
  u16* wkb = (u16*)p; p += (size_t)D * D * 2;
  u16* wvb = (u16*)p; p += (size_t)D * D * 2;
  u16* wob = (u16*)p; p += (size_t)D * D * 2;
  u16* Qb  = (u16*)p; p += (size_t)T * D * 2;
  u16* Kb  = (u16*)p; p += (size_t)T * D * 2;
  u16* VTb = (u16*)p; p += (size_t)D * T * 2;  // V^T [D][T]
  u16* Ab  = xb;  // xb dead after QKV gemm -> reuse for attn output

  // single convert launch: x (8192 blocks) + 4 weights (4096 blocks)
  cvt_all_kernel<<<dim3(12288), dim3(256), 0, stream>>>(x, Wq, Wk, Wv, Wo,
                                                        xb, wqb, wkb, wvb, wob);

  // 128^2 dbuf QKV: 8 xcd x 3 gemm x 8 byi x 8 bx = 1536 blocks; 3 exact rounds @ 2/CU
  gemm_qkv_kernel<<<dim3(1536), dim3(256), 0, stream>>>(xb, wqb, wkb, wvb, Qb, Kb, VTb, T, D);

  // attn v8: 64 bh x 8 strips, 256-thr blocks, all co-resident, KVB=128
  attn_kernel<<<dim3(B * H, 8), dim3(256), 0, stream>>>(Qb, Kb, VTb, Ab, S, H, D, T);

  gemm_out_kernel<<<dim3(512), dim3(256), 0, stream>>>(Ab, wob, out, T, D);
}